// Round 2
// baseline (737.388 us; speedup 1.0000x reference)
//
#include <hip/hip_runtime.h>
#include <hip/hip_bf16.h>
#include <math.h>

using bf16 = __hip_bfloat16;

typedef __bf16 bf16x8 __attribute__((ext_vector_type(8)));
typedef float f32x4 __attribute__((ext_vector_type(4)));

__device__ __forceinline__ float bf2f(bf16 v) { return __bfloat162float(v); }
__device__ __forceinline__ bf16 f2bf(float v) { return __float2bfloat16(v); }
__device__ __forceinline__ float nz(float v) { return (v == v) ? v : 0.0f; }

// async global -> LDS, 16 bytes per lane (wave writes base + lane*16)
__device__ __forceinline__ void gload_lds16(const void* g, void* l) {
    __builtin_amdgcn_global_load_lds(
        (const __attribute__((address_space(1))) unsigned int*)g,
        (__attribute__((address_space(3))) unsigned int*)l, 16, 0, 0);
}

// Problem constants
#define CDIM 192
#define NHEADS 6
#define ROWS 131072        // 8 * 128 * 128
#define HIDDEN 768

// ---------------------------------------------------------------------------
// K1: LN1 + cyclic shift (-4,-4) + window partition. One wave per token.
// fp32 in -> bf16 out (xw).
// ---------------------------------------------------------------------------
__global__ __launch_bounds__(256) void k_ln1_part(const float* __restrict__ x,
                                                  const float* __restrict__ g,
                                                  const float* __restrict__ bta,
                                                  bf16* __restrict__ xw) {
    int tid = threadIdx.x;
    int lane = tid & 63;
    int t = (blockIdx.x << 2) + (tid >> 6);   // chunk-local token id
    int w = t >> 6, n = t & 63;
    int bb = w >> 8, wy = (w >> 4) & 15, wx = w & 15;
    int iy = n >> 3, ix = n & 7;
    int hs = (wy * 8 + iy + 4) & 127;
    int vs = (wx * 8 + ix + 4) & 127;
    const float* xr = x + ((size_t)bb * 16384 + (size_t)hs * 128 + vs) * CDIM;
    float v0 = nz(xr[lane]);
    float v1 = nz(xr[lane + 64]);
    float v2 = nz(xr[lane + 128]);
    float s = v0 + v1 + v2;
    float q = v0 * v0 + v1 * v1 + v2 * v2;
#pragma unroll
    for (int o = 32; o > 0; o >>= 1) { s += __shfl_xor(s, o); q += __shfl_xor(q, o); }
    float mean = s * (1.0f / 192.0f);
    float var = q * (1.0f / 192.0f) - mean * mean;
    float rs = rsqrtf(var + 1e-5f);
    bf16* orow = xw + (size_t)t * CDIM;
    orow[lane]       = f2bf((v0 - mean) * rs * g[lane]       + bta[lane]);
    orow[lane + 64]  = f2bf((v1 - mean) * rs * g[lane + 64]  + bta[lane + 64]);
    orow[lane + 128] = f2bf((v2 - mean) * rs * g[lane + 128] + bta[lane + 128]);
}

// ---------------------------------------------------------------------------
// Weight transpose + fp32->bf16: in[K,N] f32 -> out[N,K] bf16
// ---------------------------------------------------------------------------
__global__ void k_transpose(const float* __restrict__ in, bf16* __restrict__ out, int K, int N) {
    int i = blockIdx.x * 256 + threadIdx.x;
    if (i < K * N) {
        int k = i / N, n = i - k * N;
        out[(size_t)n * K + k] = f2bf(in[i]);
    }
}

// ---------------------------------------------------------------------------
// Dynamic position-bias MLP (all fp32): 225 rows, 3 stages of LN->ReLU->W.
// ---------------------------------------------------------------------------
__global__ __launch_bounds__(256) void k_posmlp(
    const float* __restrict__ pp_w, const float* __restrict__ pp_b,
    const float* __restrict__ p1_g, const float* __restrict__ p1_b,
    const float* __restrict__ p1_w, const float* __restrict__ p1_bias,
    const float* __restrict__ p2_g, const float* __restrict__ p2_b,
    const float* __restrict__ p2_w, const float* __restrict__ p2_bias,
    const float* __restrict__ p3_g, const float* __restrict__ p3_b,
    const float* __restrict__ p3_w, const float* __restrict__ p3_bias,
    float* __restrict__ pos) {
    int i = threadIdx.x;
    if (i >= 225) return;
    float bh = (float)(i / 15 - 7), bw = (float)(i % 15 - 7);
    float v[12], u[12];
#pragma unroll
    for (int j = 0; j < 12; j++)
        v[j] = bh * pp_w[j] + bw * pp_w[12 + j] + pp_b[j];

    auto stage = [&](const float* gg, const float* bb2, const float* Wm, const float* bs, int OD) {
        float mean = 0.f;
        for (int j = 0; j < 12; j++) mean += v[j];
        mean *= (1.0f / 12.0f);
        float var = 0.f;
        for (int j = 0; j < 12; j++) { float d = v[j] - mean; var += d * d; }
        var *= (1.0f / 12.0f);
        float rs = rsqrtf(var + 1e-5f);
        for (int j = 0; j < 12; j++)
            u[j] = fmaxf((v[j] - mean) * rs * gg[j] + bb2[j], 0.0f);
        for (int o = 0; o < OD; o++) {
            float a = bs[o];
            for (int j = 0; j < 12; j++) a += u[j] * Wm[j * OD + o];
            v[o] = a;
        }
    };
    stage(p1_g, p1_b, p1_w, p1_bias, 12);
    stage(p2_g, p2_b, p2_w, p2_bias, 12);
    stage(p3_g, p3_b, p3_w, p3_bias, 6);
    for (int h = 0; h < 6; h++) pos[i * 6 + h] = v[h];
}

// ---------------------------------------------------------------------------
// MFMA GEMM, 2-phase double-buffered (T3 minimum recipe):
// C[M,N] = act(A[M,K] @ W[K,N] + bias) (+ residual).
// Tile 128x64, BK=64, 4 waves, each wave a 32x64 sub-tile (2x4 fragments).
// Staging via global_load_lds width=16 into linear LDS; XOR-swizzled
// global source + swizzled ds_read -> conflict-free b128 reads.
// Prologue stages buf0; each iter: issue next tile's loads into buf^1,
// compute current buf, single __syncthreads (compiler drains vmcnt) per tile.
// LDS 48KB -> 3 blocks/CU. grid = (N/64, M/128).
// ---------------------------------------------------------------------------
template <int ACT, int RESID, typename OutT>
__global__ __launch_bounds__(256) void k_gemm(const bf16* __restrict__ A,
                                              const bf16* __restrict__ Bt,
                                              const float* __restrict__ bias,
                                              OutT* __restrict__ Cd,
                                              int M, int N, int K) {
    constexpr int BM = 128, BN = 64, BK = 64;
    __shared__ __align__(16) unsigned short As[2][BM * BK];  // 2 x 16 KB
    __shared__ __align__(16) unsigned short Bs[2][BN * BK];  // 2 x 8 KB
    int tid = threadIdx.x;
    int wv = tid >> 6, lane = tid & 63;
    int lm = lane & 15, quad = lane >> 4;
    int sub = lane >> 3;                       // row-within-8 for staging
    int cb8 = (((lane & 7) ^ sub) << 3);       // inverse-swizzled bf16 col
    int n0 = blockIdx.x * BN;
    int m0 = blockIdx.y * BM;

    // staging source base pointers (per-lane)
    const bf16* aSrc = A  + (size_t)(m0 + wv * 32 + sub) * K + cb8;
    const bf16* bSrc = Bt + (size_t)(n0 + wv * 16 + sub) * K + cb8;

    // per-wave LDS chunk bases (wave-uniform; chunk = 8 rows x 64 bf16 = 1 KB)
    auto stage = [&](int buf, int k0) {
#pragma unroll
        for (int i = 0; i < 4; ++i)
            gload_lds16(aSrc + (size_t)(i * 8) * K + k0,
                        &As[buf][(wv * 32 + i * 8) * 64]);
#pragma unroll
        for (int i = 0; i < 2; ++i)
            gload_lds16(bSrc + (size_t)(i * 8) * K + k0,
                        &Bs[buf][(wv * 16 + i * 8) * 64]);
    };

    f32x4 acc[2][4] = {};

    auto compute = [&](int buf) {
#pragma unroll
        for (int ks = 0; ks < BK; ks += 32) {
            int xk = (ks + quad * 8) ^ ((lm & 7) << 3);  // swizzled read col
            bf16x8 af[2], bq[4];
#pragma unroll
            for (int im = 0; im < 2; ++im)
                af[im] = *(const bf16x8*)&As[buf][(wv * 32 + im * 16 + lm) * 64 + xk];
#pragma unroll
            for (int in = 0; in < 4; ++in)
                bq[in] = *(const bf16x8*)&Bs[buf][(in * 16 + lm) * 64 + xk];
#pragma unroll
            for (int im = 0; im < 2; ++im)
#pragma unroll
                for (int in = 0; in < 4; ++in)
                    acc[im][in] = __builtin_amdgcn_mfma_f32_16x16x32_bf16(
                        af[im], bq[in], acc[im][in], 0, 0, 0);
        }
    };

    const int nt = K / BK;
    stage(0, 0);
    __syncthreads();           // buf0 resident
    int cur = 0;
    for (int t = 0; t < nt - 1; ++t) {
        stage(cur ^ 1, (t + 1) * BK);   // issue next tile first (overlaps compute)
        compute(cur);
        __syncthreads();       // drains vmcnt(0): next buf resident; cur reusable
        cur ^= 1;
    }
    compute(cur);

    // epilogue: C/D layout col=lane&15, row=quad*4+reg
#pragma unroll
    for (int im = 0; im < 2; ++im) {
        int rbase = m0 + wv * 32 + im * 16 + quad * 4;
#pragma unroll
        for (int in = 0; in < 4; ++in) {
            int cg = n0 + in * 16 + lm;
            float bv = bias[cg];
#pragma unroll
            for (int r = 0; r < 4; ++r) {
                float v = acc[im][in][r] + bv;
                if (ACT == 1) v = 0.5f * v * (1.0f + erff(v * 0.70710678118654752f));
                size_t o = (size_t)(rbase + r) * N + cg;
                if (RESID) v += (float)Cd[o];
                Cd[o] = (OutT)v;
            }
        }
    }
}

// ---------------------------------------------------------------------------
// MFMA attention: one block per window, 4 waves, 6 heads sequential.
// Per head: S = Q·K^T (4 MFMAs/wave), softmax in C/D-layout registers,
// P -> LDS, PV = P·Vt (4 MFMAs/wave). qkv bf16 in, bf16 out.
// ---------------------------------------------------------------------------
__global__ __launch_bounds__(256) void k_attn(const bf16* __restrict__ qkv,
                                              const float* __restrict__ pos,
                                              bf16* __restrict__ outp) {
    __shared__ __align__(16) unsigned short Qs[64 * 40];  // 32 + 8 pad
    __shared__ __align__(16) unsigned short Ks[64 * 40];
    __shared__ __align__(16) unsigned short Vt[32 * 72];  // transposed: [d][m], 64 + 8 pad
    __shared__ __align__(16) unsigned short Ps[64 * 72];
    int w = blockIdx.x, tid = threadIdx.x;
    int wv = tid >> 6, lane = tid & 63;
    int lm = lane & 15, quad = lane >> 4;
    int wy = (w >> 4) & 15, wx = w & 15;
    bool edge = (wy == 15) || (wx == 15);
    const float scale = 0.17677669529663687f;  // 32^-0.5

    // staging coords: thread covers 8 contiguous bf16 of one row's head-slice
    int srow = tid >> 2, scol = (tid & 3) << 3;
    const unsigned short* gq =
        (const unsigned short*)qkv + ((size_t)w * 64 + srow) * 576 + scol;

    // precompute per-lane score coords (row n varies with quad/r; col m with ct/lm)
    int nbase = wv * 16 + quad * 4;

    for (int h = 0; h < 6; ++h) {
        // ---- stage Q, K, V(transposed) for this head ----
        uint4 uq = *(const uint4*)(gq + h * 32);
        uint4 uk = *(const uint4*)(gq + h * 32 + 192);
        uint4 uv = *(const uint4*)(gq + h * 32 + 384);
        *(uint4*)&Qs[srow * 40 + scol] = uq;
        *(uint4*)&Ks[srow * 40 + scol] = uk;
        const unsigned short* pv = (const unsigned short*)&uv;
#pragma unroll
        for (int j = 0; j < 8; j++) Vt[(scol + j) * 72 + srow] = pv[j];
        __syncthreads();

        // ---- S = Q K^T : wave wv owns query rows [wv*16, wv*16+16) ----
        f32x4 acc[4];
        bf16x8 af = *(const bf16x8*)&Qs[(wv * 16 + lm) * 40 + quad * 8];
#pragma unroll
        for (int ct = 0; ct < 4; ++ct) {
            bf16x8 bfk = *(const bf16x8*)&Ks[(ct * 16 + lm) * 40 + quad * 8];
            f32x4 z = {0.f, 0.f, 0.f, 0.f};
            acc[ct] = __builtin_amdgcn_mfma_f32_16x16x32_bf16(af, bfk, z, 0, 0, 0);
        }

        // ---- + scale + pos bias + shift mask (lane: n=nbase+r, m=ct*16+lm) ----
        float sv[4][4];
#pragma unroll
        for (int ct = 0; ct < 4; ++ct) {
            int m = ct * 16 + lm;
            int iym = m >> 3, ixm = m & 7;
            int hm = wy * 8 + iym, wm = wx * 8 + ixm;
            int ridm = (hm < 120 ? 0 : (hm < 124 ? 1 : 2)) * 3 +
                       (wm < 120 ? 0 : (wm < 124 ? 1 : 2));
#pragma unroll
            for (int r = 0; r < 4; r++) {
                int n = nbase + r;
                int iyn = n >> 3, ixn = n & 7;
                float s = acc[ct][r] * scale +
                          pos[((iyn - iym + 7) * 15 + (ixn - ixm + 7)) * 6 + h];
                if (edge) {
                    int hn = wy * 8 + iyn, wn = wx * 8 + ixn;
                    int ridn = (hn < 120 ? 0 : (hn < 124 ? 1 : 2)) * 3 +
                               (wn < 120 ? 0 : (wn < 124 ? 1 : 2));
                    if (ridn != ridm) s -= 100.0f;
                }
                sv[ct][r] = s;
            }
        }

        // ---- softmax over 64 cols: reduce 4 regs + 16-lane shuffle group ----
#pragma unroll
        for (int r = 0; r < 4; r++) {
            float mx = fmaxf(fmaxf(sv[0][r], sv[1][r]), fmaxf(sv[2][r], sv[3][r]));
#pragma unroll
            for (int o = 1; o < 16; o <<= 1) mx = fmaxf(mx, __shfl_xor(mx, o));
            float e0 = expf(sv[0][r] - mx), e1 = expf(sv[1][r] - mx);
            float e2 = expf(sv[2][r] - mx), e3 = expf(sv[3][r] - mx);
            float sum = e0 + e1 + e2 + e3;
#pragma unroll
            for (int o = 1; o < 16; o <<= 1) sum += __shfl_xor(sum, o);
            float inv = 1.0f / sum;
            int n = nbase + r;
            *(bf16*)&Ps[n * 72 + lm]      = f2bf(e0 * inv);
            *(bf16*)&Ps[n * 72 + 16 + lm] = f2bf(e1 * inv);
            *(bf16*)&Ps[n * 72 + 32 + lm] = f2bf(e2 * inv);
            *(bf16*)&Ps[n * 72 + 48 + lm] = f2bf(e3 * inv);
        }
        __syncthreads();

        // ---- PV: out rows [wv*16,+16), cols d 0..31 (2 tiles), K=64 ----
        f32x4 o0 = {0.f, 0.f, 0.f, 0.f}, o1 = {0.f, 0.f, 0.f, 0.f};
#pragma unroll
        for (int kc = 0; kc < 2; kc++) {
            bf16x8 pa = *(const bf16x8*)&Ps[(wv * 16 + lm) * 72 + kc * 32 + quad * 8];
            bf16x8 vb0 = *(const bf16x8*)&Vt[lm * 72 + kc * 32 + quad * 8];
            bf16x8 vb1 = *(const bf16x8*)&Vt[(16 + lm) * 72 + kc * 32 + quad * 8];
            o0 = __builtin_amdgcn_mfma_f32_16x16x32_bf16(pa, vb0, o0, 0, 0, 0);
            o1 = __builtin_amdgcn_mfma_f32_16x16x32_bf16(pa, vb1, o1, 0, 0, 0);
        }
#pragma unroll
        for (int r = 0; r < 4; r++) {
            int n = nbase + r;
            size_t base = ((size_t)w * 64 + n) * 192 + h * 32;
            outp[base + lm]      = f2bf(o0[r]);
            outp[base + 16 + lm] = f2bf(o1[r]);
        }
        __syncthreads();  // before next head's staging overwrites Q/K/Vt
    }
}

// ---------------------------------------------------------------------------
// K5: window reverse + shift back (+4,+4) + residual -> y (fp32 d_out),
// then LN2(y) -> h2 (bf16).
// ---------------------------------------------------------------------------
__global__ __launch_bounds__(256) void k_resid_ln2(const float* __restrict__ x,
                                                   const bf16* __restrict__ proj,
                                                   const float* __restrict__ g,
                                                   const float* __restrict__ bta,
                                                   float* __restrict__ yout,
                                                   bf16* __restrict__ h2) {
    int tid = threadIdx.x, lane = tid & 63;
    int t = (blockIdx.x << 2) + (tid >> 6);
    int bb = t >> 14, l = t & 16383;
    int h = l >> 7, ww = l & 127;
    int hr = (h + 124) & 127, wr = (ww + 124) & 127;  // (h-4) mod 128
    int win = bb * 256 + (hr >> 3) * 16 + (wr >> 3);
    int n = ((hr & 7) << 3) + (wr & 7);
    const float* xr = x + (size_t)t * CDIM;
    const bf16* pr = proj + ((size_t)win * 64 + n) * CDIM;
    float v0 = nz(xr[lane])       + bf2f(pr[lane]);
    float v1 = nz(xr[lane + 64])  + bf2f(pr[lane + 64]);
    float v2 = nz(xr[lane + 128]) + bf2f(pr[lane + 128]);
    float* yr = yout + (size_t)t * CDIM;
    yr[lane]       = v0;
    yr[lane + 64]  = v1;
    yr[lane + 128] = v2;
    float s = v0 + v1 + v2;
    float q = v0 * v0 + v1 * v1 + v2 * v2;
#pragma unroll
    for (int o = 32; o > 0; o >>= 1) { s += __shfl_xor(s, o); q += __shfl_xor(q, o); }
    float mean = s * (1.0f / 192.0f);
    float var = q * (1.0f / 192.0f) - mean * mean;
    float rs = rsqrtf(var + 1e-5f);
    bf16* hr2 = h2 + (size_t)t * CDIM;
    hr2[lane]       = f2bf((v0 - mean) * rs * g[lane]       + bta[lane]);
    hr2[lane + 64]  = f2bf((v1 - mean) * rs * g[lane + 64]  + bta[lane + 64]);
    hr2[lane + 128] = f2bf((v2 - mean) * rs * g[lane + 128] + bta[lane + 128]);
}

// ---------------------------------------------------------------------------
extern "C" void kernel_launch(void* const* d_in, const int* in_sizes, int n_in,
                              void* d_out, int out_size, void* d_ws, size_t ws_size,
                              hipStream_t stream) {
    (void)in_sizes; (void)n_in; (void)out_size;
    const float* x      = (const float*)d_in[0];
    const float* n1_g   = (const float*)d_in[4];
    const float* n1_b   = (const float*)d_in[5];
    const float* qkv_w  = (const float*)d_in[6];
    const float* qkv_b  = (const float*)d_in[7];
    const float* proj_w = (const float*)d_in[8];
    const float* proj_b = (const float*)d_in[9];
    const float* pp_w   = (const float*)d_in[10];
    const float* pp_b   = (const float*)d_in[11];
    const float* p1_g   = (const float*)d_in[12];
    const float* p1_b   = (const float*)d_in[13];
    const float* p1_w   = (const float*)d_in[14];
    const float* p1_bias= (const float*)d_in[15];
    const float* p2_g   = (const float*)d_in[16];
    const float* p2_b   = (const float*)d_in[17];
    const float* p2_w   = (const float*)d_in[18];
    const float* p2_bias= (const float*)d_in[19];
    const float* p3_g   = (const float*)d_in[20];
    const float* p3_b   = (const float*)d_in[21];
    const float* p3_w   = (const float*)d_in[22];
    const float* p3_bias= (const float*)d_in[23];
    const float* n2_g   = (const float*)d_in[24];
    const float* n2_b   = (const float*)d_in[25];
    const float* fc1_w  = (const float*)d_in[26];
    const float* fc1_b  = (const float*)d_in[27];
    const float* fc2_w  = (const float*)d_in[28];
    const float* fc2_b  = (const float*)d_in[29];

    char* ws = (char*)d_ws;
    size_t off = 0;
    auto alloc = [&](size_t bytes) -> char* {
        char* p = ws + off;
        off += (bytes + 255) & ~(size_t)255;
        return p;
    };
    // bf16 weight copies + pos (~0.9 MB)
    bf16* qkvwT  = (bf16*)alloc((size_t)CDIM * 576 * 2);
    bf16* projwT = (bf16*)alloc((size_t)CDIM * CDIM * 2);
    bf16* fc1wT  = (bf16*)alloc((size_t)CDIM * HIDDEN * 2);
    bf16* fc2wT  = (bf16*)alloc((size_t)HIDDEN * CDIM * 2);
    float* pos   = (float*)alloc(225 * 6 * 4);

    const size_t flatNeed = (size_t)ROWS * CDIM * 2 + (size_t)ROWS * HIDDEN * 2 + (1u << 20);
    const bool flat = (ws_size > off) && ((ws_size - off) >= flatNeed);
    const int NCH = flat ? 1 : 8;
    const int NIMG = flat ? 8 : 1;
    const size_t R = (size_t)16384 * NIMG;   // rows per chunk

    bf16 *xw_b, *qkv_buf, *attn_b, *proj_buf, *h2_b, *fc1_buf;
    if (flat) {
        bf16* region0 = (bf16*)alloc((size_t)ROWS * CDIM * 2);
        bf16* region1 = (bf16*)alloc((size_t)ROWS * HIDDEN * 2);
        xw_b = attn_b = h2_b = region0;            // sequential lifetimes
        qkv_buf  = region1;
        proj_buf = region1 + (size_t)ROWS * 576;
        fc1_buf  = region1;                        // qkv/proj dead by then
    } else {
        xw_b     = (bf16*)alloc(R * CDIM * 2);
        qkv_buf  = (bf16*)alloc(R * 576 * 2);
        attn_b   = (bf16*)alloc(R * CDIM * 2);
        proj_buf = (bf16*)alloc(R * CDIM * 2);
        h2_b     = (bf16*)alloc(R * CDIM * 2);
        fc1_buf  = (bf16*)alloc(R * HIDDEN * 2);
    }
    float* yout = (float*)d_out;

    // prep (tiny)
    k_transpose<<<(CDIM * 576 + 255) / 256, 256, 0, stream>>>(qkv_w, qkvwT, CDIM, 576);
    k_transpose<<<(CDIM * CDIM + 255) / 256, 256, 0, stream>>>(proj_w, projwT, CDIM, CDIM);
    k_transpose<<<(CDIM * HIDDEN + 255) / 256, 256, 0, stream>>>(fc1_w, fc1wT, CDIM, HIDDEN);
    k_transpose<<<(HIDDEN * CDIM + 255) / 256, 256, 0, stream>>>(fc2_w, fc2wT, HIDDEN, CDIM);
    k_posmlp<<<1, 256, 0, stream>>>(pp_w, pp_b, p1_g, p1_b, p1_w, p1_bias,
                                    p2_g, p2_b, p2_w, p2_bias,
                                    p3_g, p3_b, p3_w, p3_bias, pos);

    for (int c = 0; c < NCH; ++c) {
        const float* x_c = x + (size_t)c * 16384 * CDIM;
        float* y_c = yout + (size_t)c * 16384 * CDIM;

        k_ln1_part<<<(int)(R / 4), 256, 0, stream>>>(x_c, n1_g, n1_b, xw_b);

        k_gemm<0, 0, bf16><<<dim3(576 / 64, (int)(R / 128)), 256, 0, stream>>>(
            xw_b, qkvwT, qkv_b, qkv_buf, (int)R, 576, CDIM);

        k_attn<<<(int)(R / 64), 256, 0, stream>>>(qkv_buf, pos, attn_b);

        k_gemm<0, 0, bf16><<<dim3(CDIM / 64, (int)(R / 128)), 256, 0, stream>>>(
            attn_b, projwT, proj_b, proj_buf, (int)R, CDIM, CDIM);

        k_resid_ln2<<<(int)(R / 4), 256, 0, stream>>>(x_c, proj_buf, n2_g, n2_b, y_c, h2_b);

        k_gemm<1, 0, bf16><<<dim3(HIDDEN / 64, (int)(R / 128)), 256, 0, stream>>>(
            h2_b, fc1wT, fc1_b, fc1_buf, (int)R, HIDDEN, CDIM);

        k_gemm<0, 1, float><<<dim3(CDIM / 64, (int)(R / 128)), 256, 0, stream>>>(
            fc1_buf, fc2wT, fc2_b, y_c, (int)R, CDIM, HIDDEN);
    }
}

// Round 3
// 731.173 us; speedup vs baseline: 1.0085x; 1.0085x over previous
//
#include <hip/hip_runtime.h>
#include <hip/hip_bf16.h>
#include <math.h>

using bf16 = __hip_bfloat16;

typedef __bf16 bf16x8 __attribute__((ext_vector_type(8)));
typedef float f32x4 __attribute__((ext_vector_type(4)));

__device__ __forceinline__ float bf2f(bf16 v) { return __bfloat162float(v); }
__device__ __forceinline__ bf16 f2bf(float v) { return __float2bfloat16(v); }
__device__ __forceinline__ float nz(float v) { return (v == v) ? v : 0.0f; }

// async global -> LDS, 16 bytes per lane (wave writes base + lane*16)
__device__ __forceinline__ void gload_lds16(const void* g, void* l) {
    __builtin_amdgcn_global_load_lds(
        (const __attribute__((address_space(1))) unsigned int*)g,
        (__attribute__((address_space(3))) unsigned int*)l, 16, 0, 0);
}

// Problem constants
#define CDIM 192
#define NHEADS 6
#define ROWS 131072        // 8 * 128 * 128
#define HIDDEN 768

// ---------------------------------------------------------------------------
// K1: LN1 + cyclic shift (-4,-4) + window partition. One wave per token.
// fp32 in -> bf16 out (xw).
// ---------------------------------------------------------------------------
__global__ __launch_bounds__(256) void k_ln1_part(const float* __restrict__ x,
                                                  const float* __restrict__ g,
                                                  const float* __restrict__ bta,
                                                  bf16* __restrict__ xw) {
    int tid = threadIdx.x;
    int lane = tid & 63;
    int t = (blockIdx.x << 2) + (tid >> 6);   // chunk-local token id
    int w = t >> 6, n = t & 63;
    int bb = w >> 8, wy = (w >> 4) & 15, wx = w & 15;
    int iy = n >> 3, ix = n & 7;
    int hs = (wy * 8 + iy + 4) & 127;
    int vs = (wx * 8 + ix + 4) & 127;
    const float* xr = x + ((size_t)bb * 16384 + (size_t)hs * 128 + vs) * CDIM;
    float v0 = nz(xr[lane]);
    float v1 = nz(xr[lane + 64]);
    float v2 = nz(xr[lane + 128]);
    float s = v0 + v1 + v2;
    float q = v0 * v0 + v1 * v1 + v2 * v2;
#pragma unroll
    for (int o = 32; o > 0; o >>= 1) { s += __shfl_xor(s, o); q += __shfl_xor(q, o); }
    float mean = s * (1.0f / 192.0f);
    float var = q * (1.0f / 192.0f) - mean * mean;
    float rs = rsqrtf(var + 1e-5f);
    bf16* orow = xw + (size_t)t * CDIM;
    orow[lane]       = f2bf((v0 - mean) * rs * g[lane]       + bta[lane]);
    orow[lane + 64]  = f2bf((v1 - mean) * rs * g[lane + 64]  + bta[lane + 64]);
    orow[lane + 128] = f2bf((v2 - mean) * rs * g[lane + 128] + bta[lane + 128]);
}

// ---------------------------------------------------------------------------
// Weight transpose + fp32->bf16: in[K,N] f32 -> out[N,K] bf16
// ---------------------------------------------------------------------------
__global__ void k_transpose(const float* __restrict__ in, bf16* __restrict__ out, int K, int N) {
    int i = blockIdx.x * 256 + threadIdx.x;
    if (i < K * N) {
        int k = i / N, n = i - k * N;
        out[(size_t)n * K + k] = f2bf(in[i]);
    }
}

// ---------------------------------------------------------------------------
// Dynamic position-bias MLP (all fp32): 225 rows, 3 stages of LN->ReLU->W.
// ---------------------------------------------------------------------------
__global__ __launch_bounds__(256) void k_posmlp(
    const float* __restrict__ pp_w, const float* __restrict__ pp_b,
    const float* __restrict__ p1_g, const float* __restrict__ p1_b,
    const float* __restrict__ p1_w, const float* __restrict__ p1_bias,
    const float* __restrict__ p2_g, const float* __restrict__ p2_b,
    const float* __restrict__ p2_w, const float* __restrict__ p2_bias,
    const float* __restrict__ p3_g, const float* __restrict__ p3_b,
    const float* __restrict__ p3_w, const float* __restrict__ p3_bias,
    float* __restrict__ pos) {
    int i = threadIdx.x;
    if (i >= 225) return;
    float bh = (float)(i / 15 - 7), bw = (float)(i % 15 - 7);
    float v[12], u[12];
#pragma unroll
    for (int j = 0; j < 12; j++)
        v[j] = bh * pp_w[j] + bw * pp_w[12 + j] + pp_b[j];

    auto stage = [&](const float* gg, const float* bb2, const float* Wm, const float* bs, int OD) {
        float mean = 0.f;
        for (int j = 0; j < 12; j++) mean += v[j];
        mean *= (1.0f / 12.0f);
        float var = 0.f;
        for (int j = 0; j < 12; j++) { float d = v[j] - mean; var += d * d; }
        var *= (1.0f / 12.0f);
        float rs = rsqrtf(var + 1e-5f);
        for (int j = 0; j < 12; j++)
            u[j] = fmaxf((v[j] - mean) * rs * gg[j] + bb2[j], 0.0f);
        for (int o = 0; o < OD; o++) {
            float a = bs[o];
            for (int j = 0; j < 12; j++) a += u[j] * Wm[j * OD + o];
            v[o] = a;
        }
    };
    stage(p1_g, p1_b, p1_w, p1_bias, 12);
    stage(p2_g, p2_b, p2_w, p2_bias, 12);
    stage(p3_g, p3_b, p3_w, p3_bias, 6);
    for (int h = 0; h < 6; h++) pos[i * 6 + h] = v[h];
}

// ---------------------------------------------------------------------------
// MFMA GEMM, 2-buffer pipeline with COUNTED vmcnt (T4):
// C[M,N] = act(A[M,K] @ W[K,N] + bias) (+ residual).
// Tile 128x64, BK=64, 4 waves, each wave a 32x64 sub-tile (2x4 fragments).
// Each wave issues 6 global_load_lds per tile. Prologue stages tiles 0,1
// (12 in flight). Per iter: s_waitcnt vmcnt(6) waits ONLY the oldest 6
// (tile t); tile t+1's loads stay in flight across the barrier and the
// whole compute phase -> memory issue never stops. Raw s_barrier (no
// compiler vmcnt(0) drain). Post-compute barrier guards buffer overwrite.
// LDS 48KB -> 3 blocks/CU. grid = (N/64, M/128).
// ---------------------------------------------------------------------------
template <int ACT, int RESID, typename OutT>
__global__ __launch_bounds__(256) void k_gemm(const bf16* __restrict__ A,
                                              const bf16* __restrict__ Bt,
                                              const float* __restrict__ bias,
                                              OutT* __restrict__ Cd,
                                              int M, int N, int K) {
    constexpr int BM = 128, BN = 64, BK = 64;
    __shared__ __align__(16) unsigned short As[2][BM * BK];  // 2 x 16 KB
    __shared__ __align__(16) unsigned short Bs[2][BN * BK];  // 2 x 8 KB
    int tid = threadIdx.x;
    int wv = tid >> 6, lane = tid & 63;
    int lm = lane & 15, quad = lane >> 4;
    int sub = lane >> 3;                       // row-within-8 for staging
    int cb8 = (((lane & 7) ^ sub) << 3);       // inverse-swizzled bf16 col
    int n0 = blockIdx.x * BN;
    int m0 = blockIdx.y * BM;

    // staging source base pointers (per-lane)
    const bf16* aSrc = A  + (size_t)(m0 + wv * 32 + sub) * K + cb8;
    const bf16* bSrc = Bt + (size_t)(n0 + wv * 16 + sub) * K + cb8;

    // 6 loads per wave per tile (wave-uniform LDS dest; chunk = 8 rows = 1 KB)
    auto stage = [&](int buf, int k0) {
#pragma unroll
        for (int i = 0; i < 4; ++i)
            gload_lds16(aSrc + (size_t)(i * 8) * K + k0,
                        &As[buf][(wv * 32 + i * 8) * 64]);
#pragma unroll
        for (int i = 0; i < 2; ++i)
            gload_lds16(bSrc + (size_t)(i * 8) * K + k0,
                        &Bs[buf][(wv * 16 + i * 8) * 64]);
    };

    f32x4 acc[2][4] = {};

    auto compute = [&](int buf) {
#pragma unroll
        for (int ks = 0; ks < BK; ks += 32) {
            int xk = (ks + quad * 8) ^ ((lm & 7) << 3);  // swizzled read col
            bf16x8 af[2], bq[4];
#pragma unroll
            for (int im = 0; im < 2; ++im)
                af[im] = *(const bf16x8*)&As[buf][(wv * 32 + im * 16 + lm) * 64 + xk];
#pragma unroll
            for (int in = 0; in < 4; ++in)
                bq[in] = *(const bf16x8*)&Bs[buf][(in * 16 + lm) * 64 + xk];
#pragma unroll
            for (int im = 0; im < 2; ++im)
#pragma unroll
                for (int in = 0; in < 4; ++in)
                    acc[im][in] = __builtin_amdgcn_mfma_f32_16x16x32_bf16(
                        af[im], bq[in], acc[im][in], 0, 0, 0);
        }
    };

    const int nt = K / BK;      // >= 3 for all shapes here
    stage(0, 0);
    if (nt > 1) stage(1, BK);
    int cur = 0;
    for (int t = 0; t < nt; ++t) {
        if (t + 1 < nt)
            asm volatile("s_waitcnt vmcnt(6)" ::: "memory");  // tile t resident, t+1 in flight
        else
            asm volatile("s_waitcnt vmcnt(0)" ::: "memory");  // last tile
        __builtin_amdgcn_s_barrier();   // collective residency of tile t
        compute(cur);
        if (t + 2 < nt) {
            __builtin_amdgcn_s_barrier();   // all waves done reading cur
            stage(cur, (t + 2) * BK);       // refill freed buffer
        }
        cur ^= 1;
    }

    // epilogue: C/D layout col=lane&15, row=quad*4+reg
#pragma unroll
    for (int im = 0; im < 2; ++im) {
        int rbase = m0 + wv * 32 + im * 16 + quad * 4;
#pragma unroll
        for (int in = 0; in < 4; ++in) {
            int cg = n0 + in * 16 + lm;
            float bv = bias[cg];
#pragma unroll
            for (int r = 0; r < 4; ++r) {
                float v = acc[im][in][r] + bv;
                if (ACT == 1) v = 0.5f * v * (1.0f + erff(v * 0.70710678118654752f));
                size_t o = (size_t)(rbase + r) * N + cg;
                if (RESID) v += (float)Cd[o];
                Cd[o] = (OutT)v;
            }
        }
    }
}

// ---------------------------------------------------------------------------
// MFMA attention: one block per window, 4 waves, 6 heads sequential.
// Per head: S = Q·K^T (4 MFMAs/wave), softmax in C/D-layout registers,
// P -> LDS, PV = P·Vt (4 MFMAs/wave). qkv bf16 in, bf16 out.
// ---------------------------------------------------------------------------
__global__ __launch_bounds__(256) void k_attn(const bf16* __restrict__ qkv,
                                              const float* __restrict__ pos,
                                              bf16* __restrict__ outp) {
    __shared__ __align__(16) unsigned short Qs[64 * 40];  // 32 + 8 pad
    __shared__ __align__(16) unsigned short Ks[64 * 40];
    __shared__ __align__(16) unsigned short Vt[32 * 72];  // transposed: [d][m], 64 + 8 pad
    __shared__ __align__(16) unsigned short Ps[64 * 72];
    int w = blockIdx.x, tid = threadIdx.x;
    int wv = tid >> 6, lane = tid & 63;
    int lm = lane & 15, quad = lane >> 4;
    int wy = (w >> 4) & 15, wx = w & 15;
    bool edge = (wy == 15) || (wx == 15);
    const float scale = 0.17677669529663687f;  // 32^-0.5

    // staging coords: thread covers 8 contiguous bf16 of one row's head-slice
    int srow = tid >> 2, scol = (tid & 3) << 3;
    const unsigned short* gq =
        (const unsigned short*)qkv + ((size_t)w * 64 + srow) * 576 + scol;

    // precompute per-lane score coords (row n varies with quad/r; col m with ct/lm)
    int nbase = wv * 16 + quad * 4;

    for (int h = 0; h < 6; ++h) {
        // ---- stage Q, K, V(transposed) for this head ----
        uint4 uq = *(const uint4*)(gq + h * 32);
        uint4 uk = *(const uint4*)(gq + h * 32 + 192);
        uint4 uv = *(const uint4*)(gq + h * 32 + 384);
        *(uint4*)&Qs[srow * 40 + scol] = uq;
        *(uint4*)&Ks[srow * 40 + scol] = uk;
        const unsigned short* pv = (const unsigned short*)&uv;
#pragma unroll
        for (int j = 0; j < 8; j++) Vt[(scol + j) * 72 + srow] = pv[j];
        __syncthreads();

        // ---- S = Q K^T : wave wv owns query rows [wv*16, wv*16+16) ----
        f32x4 acc[4];
        bf16x8 af = *(const bf16x8*)&Qs[(wv * 16 + lm) * 40 + quad * 8];
#pragma unroll
        for (int ct = 0; ct < 4; ++ct) {
            bf16x8 bfk = *(const bf16x8*)&Ks[(ct * 16 + lm) * 40 + quad * 8];
            f32x4 z = {0.f, 0.f, 0.f, 0.f};
            acc[ct] = __builtin_amdgcn_mfma_f32_16x16x32_bf16(af, bfk, z, 0, 0, 0);
        }

        // ---- + scale + pos bias + shift mask (lane: n=nbase+r, m=ct*16+lm) ----
        float sv[4][4];
#pragma unroll
        for (int ct = 0; ct < 4; ++ct) {
            int m = ct * 16 + lm;
            int iym = m >> 3, ixm = m & 7;
            int hm = wy * 8 + iym, wm = wx * 8 + ixm;
            int ridm = (hm < 120 ? 0 : (hm < 124 ? 1 : 2)) * 3 +
                       (wm < 120 ? 0 : (wm < 124 ? 1 : 2));
#pragma unroll
            for (int r = 0; r < 4; r++) {
                int n = nbase + r;
                int iyn = n >> 3, ixn = n & 7;
                float s = acc[ct][r] * scale +
                          pos[((iyn - iym + 7) * 15 + (ixn - ixm + 7)) * 6 + h];
                if (edge) {
                    int hn = wy * 8 + iyn, wn = wx * 8 + ixn;
                    int ridn = (hn < 120 ? 0 : (hn < 124 ? 1 : 2)) * 3 +
                               (wn < 120 ? 0 : (wn < 124 ? 1 : 2));
                    if (ridn != ridm) s -= 100.0f;
                }
                sv[ct][r] = s;
            }
        }

        // ---- softmax over 64 cols: reduce 4 regs + 16-lane shuffle group ----
#pragma unroll
        for (int r = 0; r < 4; r++) {
            float mx = fmaxf(fmaxf(sv[0][r], sv[1][r]), fmaxf(sv[2][r], sv[3][r]));
#pragma unroll
            for (int o = 1; o < 16; o <<= 1) mx = fmaxf(mx, __shfl_xor(mx, o));
            float e0 = expf(sv[0][r] - mx), e1 = expf(sv[1][r] - mx);
            float e2 = expf(sv[2][r] - mx), e3 = expf(sv[3][r] - mx);
            float sum = e0 + e1 + e2 + e3;
#pragma unroll
            for (int o = 1; o < 16; o <<= 1) sum += __shfl_xor(sum, o);
            float inv = 1.0f / sum;
            int n = nbase + r;
            *(bf16*)&Ps[n * 72 + lm]      = f2bf(e0 * inv);
            *(bf16*)&Ps[n * 72 + 16 + lm] = f2bf(e1 * inv);
            *(bf16*)&Ps[n * 72 + 32 + lm] = f2bf(e2 * inv);
            *(bf16*)&Ps[n * 72 + 48 + lm] = f2bf(e3 * inv);
        }
        __syncthreads();

        // ---- PV: out rows [wv*16,+16), cols d 0..31 (2 tiles), K=64 ----
        f32x4 o0 = {0.f, 0.f, 0.f, 0.f}, o1 = {0.f, 0.f, 0.f, 0.f};
#pragma unroll
        for (int kc = 0; kc < 2; kc++) {
            bf16x8 pa = *(const bf16x8*)&Ps[(wv * 16 + lm) * 72 + kc * 32 + quad * 8];
            bf16x8 vb0 = *(const bf16x8*)&Vt[lm * 72 + kc * 32 + quad * 8];
            bf16x8 vb1 = *(const bf16x8*)&Vt[(16 + lm) * 72 + kc * 32 + quad * 8];
            o0 = __builtin_amdgcn_mfma_f32_16x16x32_bf16(pa, vb0, o0, 0, 0, 0);
            o1 = __builtin_amdgcn_mfma_f32_16x16x32_bf16(pa, vb1, o1, 0, 0, 0);
        }
#pragma unroll
        for (int r = 0; r < 4; r++) {
            int n = nbase + r;
            size_t base = ((size_t)w * 64 + n) * 192 + h * 32;
            outp[base + lm]      = f2bf(o0[r]);
            outp[base + 16 + lm] = f2bf(o1[r]);
        }
        __syncthreads();  // before next head's staging overwrites Q/K/Vt
    }
}

// ---------------------------------------------------------------------------
// K5: window reverse + shift back (+4,+4) + residual -> y (fp32 d_out),
// then LN2(y) -> h2 (bf16).
// ---------------------------------------------------------------------------
__global__ __launch_bounds__(256) void k_resid_ln2(const float* __restrict__ x,
                                                   const bf16* __restrict__ proj,
                                                   const float* __restrict__ g,
                                                   const float* __restrict__ bta,
                                                   float* __restrict__ yout,
                                                   bf16* __restrict__ h2) {
    int tid = threadIdx.x, lane = tid & 63;
    int t = (blockIdx.x << 2) + (tid >> 6);
    int bb = t >> 14, l = t & 16383;
    int h = l >> 7, ww = l & 127;
    int hr = (h + 124) & 127, wr = (ww + 124) & 127;  // (h-4) mod 128
    int win = bb * 256 + (hr >> 3) * 16 + (wr >> 3);
    int n = ((hr & 7) << 3) + (wr & 7);
    const float* xr = x + (size_t)t * CDIM;
    const bf16* pr = proj + ((size_t)win * 64 + n) * CDIM;
    float v0 = nz(xr[lane])       + bf2f(pr[lane]);
    float v1 = nz(xr[lane + 64])  + bf2f(pr[lane + 64]);
    float v2 = nz(xr[lane + 128]) + bf2f(pr[lane + 128]);
    float* yr = yout + (size_t)t * CDIM;
    yr[lane]       = v0;
    yr[lane + 64]  = v1;
    yr[lane + 128] = v2;
    float s = v0 + v1 + v2;
    float q = v0 * v0 + v1 * v1 + v2 * v2;
#pragma unroll
    for (int o = 32; o > 0; o >>= 1) { s += __shfl_xor(s, o); q += __shfl_xor(q, o); }
    float mean = s * (1.0f / 192.0f);
    float var = q * (1.0f / 192.0f) - mean * mean;
    float rs = rsqrtf(var + 1e-5f);
    bf16* hr2 = h2 + (size_t)t * CDIM;
    hr2[lane]       = f2bf((v0 - mean) * rs * g[lane]       + bta[lane]);
    hr2[lane + 64]  = f2bf((v1 - mean) * rs * g[lane + 64]  + bta[lane + 64]);
    hr2[lane + 128] = f2bf((v2 - mean) * rs * g[lane + 128] + bta[lane + 128]);
}

// ---------------------------------------------------------------------------
extern "C" void kernel_launch(void* const* d_in, const int* in_sizes, int n_in,
                              void* d_out, int out_size, void* d_ws, size_t ws_size,
                              hipStream_t stream) {
    (void)in_sizes; (void)n_in; (void)out_size;
    const float* x      = (const float*)d_in[0];
    const float* n1_g   = (const float*)d_in[4];
    const float* n1_b   = (const float*)d_in[5];
    const float* qkv_w  = (const float*)d_in[6];
    const float* qkv_b  = (const float*)d_in[7];
    const float* proj_w = (const float*)d_in[8];
    const float* proj_b = (const float*)d_in[9];
    const float* pp_w   = (const float*)d_in[10];
    const float* pp_b   = (const float*)d_in[11];
    const float* p1_g   = (const float*)d_in[12];
    const float* p1_b   = (const float*)d_in[13];
    const float* p1_w   = (const float*)d_in[14];
    const float* p1_bias= (const float*)d_in[15];
    const float* p2_g   = (const float*)d_in[16];
    const float* p2_b   = (const float*)d_in[17];
    const float* p2_w   = (const float*)d_in[18];
    const float* p2_bias= (const float*)d_in[19];
    const float* p3_g   = (const float*)d_in[20];
    const float* p3_b   = (const float*)d_in[21];
    const float* p3_w   = (const float*)d_in[22];
    const float* p3_bias= (const float*)d_in[23];
    const float* n2_g   = (const float*)d_in[24];
    const float* n2_b   = (const float*)d_in[25];
    const float* fc1_w  = (const float*)d_in[26];
    const float* fc1_b  = (const float*)d_in[27];
    const float* fc2_w  = (const float*)d_in[28];
    const float* fc2_b  = (const float*)d_in[29];

    char* ws = (char*)d_ws;
    size_t off = 0;
    auto alloc = [&](size_t bytes) -> char* {
        char* p = ws + off;
        off += (bytes + 255) & ~(size_t)255;
        return p;
    };
    // bf16 weight copies + pos (~0.9 MB)
    bf16* qkvwT  = (bf16*)alloc((size_t)CDIM * 576 * 2);
    bf16* projwT = (bf16*)alloc((size_t)CDIM * CDIM * 2);
    bf16* fc1wT  = (bf16*)alloc((size_t)CDIM * HIDDEN * 2);
    bf16* fc2wT  = (bf16*)alloc((size_t)HIDDEN * CDIM * 2);
    float* pos   = (float*)alloc(225 * 6 * 4);

    const size_t flatNeed = (size_t)ROWS * CDIM * 2 + (size_t)ROWS * HIDDEN * 2 + (1u << 20);
    const bool flat = (ws_size > off) && ((ws_size - off) >= flatNeed);
    const int NCH = flat ? 1 : 8;
    const int NIMG = flat ? 8 : 1;
    const size_t R = (size_t)16384 * NIMG;   // rows per chunk

    bf16 *xw_b, *qkv_buf, *attn_b, *proj_buf, *h2_b, *fc1_buf;
    if (flat) {
        bf16* region0 = (bf16*)alloc((size_t)ROWS * CDIM * 2);
        bf16* region1 = (bf16*)alloc((size_t)ROWS * HIDDEN * 2);
        xw_b = attn_b = h2_b = region0;            // sequential lifetimes
        qkv_buf  = region1;
        proj_buf = region1 + (size_t)ROWS * 576;
        fc1_buf  = region1;                        // qkv/proj dead by then
    } else {
        xw_b     = (bf16*)alloc(R * CDIM * 2);
        qkv_buf  = (bf16*)alloc(R * 576 * 2);
        attn_b   = (bf16*)alloc(R * CDIM * 2);
        proj_buf = (bf16*)alloc(R * CDIM * 2);
        h2_b     = (bf16*)alloc(R * CDIM * 2);
        fc1_buf  = (bf16*)alloc(R * HIDDEN * 2);
    }
    float* yout = (float*)d_out;

    // prep (tiny)
    k_transpose<<<(CDIM * 576 + 255) / 256, 256, 0, stream>>>(qkv_w, qkvwT, CDIM, 576);
    k_transpose<<<(CDIM * CDIM + 255) / 256, 256, 0, stream>>>(proj_w, projwT, CDIM, CDIM);
    k_transpose<<<(CDIM * HIDDEN + 255) / 256, 256, 0, stream>>>(fc1_w, fc1wT, CDIM, HIDDEN);
    k_transpose<<<(HIDDEN * CDIM + 255) / 256, 256, 0, stream>>>(fc2_w, fc2wT, HIDDEN, CDIM);
    k_posmlp<<<1, 256, 0, stream>>>(pp_w, pp_b, p1_g, p1_b, p1_w, p1_bias,
                                    p2_g, p2_b, p2_w, p2_bias,
                                    p3_g, p3_b, p3_w, p3_bias, pos);

    for (int c = 0; c < NCH; ++c) {
        const float* x_c = x + (size_t)c * 16384 * CDIM;
        float* y_c = yout + (size_t)c * 16384 * CDIM;

        k_ln1_part<<<(int)(R / 4), 256, 0, stream>>>(x_c, n1_g, n1_b, xw_b);

        k_gemm<0, 0, bf16><<<dim3(576 / 64, (int)(R / 128)), 256, 0, stream>>>(
            xw_b, qkvwT, qkv_b, qkv_buf, (int)R, 576, CDIM);

        k_attn<<<(int)(R / 64), 256, 0, stream>>>(qkv_buf, pos, attn_b);

        k_gemm<0, 0, bf16><<<dim3(CDIM / 64, (int)(R / 128)), 256, 0, stream>>>(
            attn_b, projwT, proj_b, proj_buf, (int)R, CDIM, CDIM);

        k_resid_ln2<<<(int)(R / 4), 256, 0, stream>>>(x_c, proj_buf, n2_g, n2_b, y_c, h2_b);

        k_gemm<1, 0, bf16><<<dim3(HIDDEN / 64, (int)(R / 128)), 256, 0, stream>>>(
            h2_b, fc1wT, fc1_b, fc1_buf, (int)R, HIDDEN, CDIM);

        k_gemm<0, 1, float><<<dim3(CDIM / 64, (int)(R / 128)), 256, 0, stream>>>(
            fc1_buf, fc2wT, fc2_b, y_c, (int)R, CDIM, HIDDEN);
    }
}

// Round 4
// 677.410 us; speedup vs baseline: 1.0885x; 1.0794x over previous
//
#include <hip/hip_runtime.h>
#include <hip/hip_bf16.h>
#include <math.h>

using bf16 = __hip_bfloat16;

typedef __bf16 bf16x8 __attribute__((ext_vector_type(8)));
typedef float f32x4 __attribute__((ext_vector_type(4)));

__device__ __forceinline__ float bf2f(bf16 v) { return __bfloat162float(v); }
__device__ __forceinline__ bf16 f2bf(float v) { return __float2bfloat16(v); }
__device__ __forceinline__ float nz(float v) { return (v == v) ? v : 0.0f; }

// async global -> LDS, 16 bytes per lane (wave writes base + lane*16)
__device__ __forceinline__ void gload_lds16(const void* g, void* l) {
    __builtin_amdgcn_global_load_lds(
        (const __attribute__((address_space(1))) unsigned int*)g,
        (__attribute__((address_space(3))) unsigned int*)l, 16, 0, 0);
}

// Problem constants
#define CDIM 192
#define NHEADS 6
#define ROWS 131072        // 8 * 128 * 128
#define HIDDEN 768

// ---------------------------------------------------------------------------
// K1: LN1 + cyclic shift (-4,-4) + window partition. One wave per token.
// fp32 in -> bf16 out (xw).
// ---------------------------------------------------------------------------
__global__ __launch_bounds__(256) void k_ln1_part(const float* __restrict__ x,
                                                  const float* __restrict__ g,
                                                  const float* __restrict__ bta,
                                                  bf16* __restrict__ xw) {
    int tid = threadIdx.x;
    int lane = tid & 63;
    int t = (blockIdx.x << 2) + (tid >> 6);   // chunk-local token id
    int w = t >> 6, n = t & 63;
    int bb = w >> 8, wy = (w >> 4) & 15, wx = w & 15;
    int iy = n >> 3, ix = n & 7;
    int hs = (wy * 8 + iy + 4) & 127;
    int vs = (wx * 8 + ix + 4) & 127;
    const float* xr = x + ((size_t)bb * 16384 + (size_t)hs * 128 + vs) * CDIM;
    float v0 = nz(xr[lane]);
    float v1 = nz(xr[lane + 64]);
    float v2 = nz(xr[lane + 128]);
    float s = v0 + v1 + v2;
    float q = v0 * v0 + v1 * v1 + v2 * v2;
#pragma unroll
    for (int o = 32; o > 0; o >>= 1) { s += __shfl_xor(s, o); q += __shfl_xor(q, o); }
    float mean = s * (1.0f / 192.0f);
    float var = q * (1.0f / 192.0f) - mean * mean;
    float rs = rsqrtf(var + 1e-5f);
    bf16* orow = xw + (size_t)t * CDIM;
    orow[lane]       = f2bf((v0 - mean) * rs * g[lane]       + bta[lane]);
    orow[lane + 64]  = f2bf((v1 - mean) * rs * g[lane + 64]  + bta[lane + 64]);
    orow[lane + 128] = f2bf((v2 - mean) * rs * g[lane + 128] + bta[lane + 128]);
}

// ---------------------------------------------------------------------------
// Weight transpose + fp32->bf16: in[K,N] f32 -> out[N,K] bf16
// ---------------------------------------------------------------------------
__global__ void k_transpose(const float* __restrict__ in, bf16* __restrict__ out, int K, int N) {
    int i = blockIdx.x * 256 + threadIdx.x;
    if (i < K * N) {
        int k = i / N, n = i - k * N;
        out[(size_t)n * K + k] = f2bf(in[i]);
    }
}

// ---------------------------------------------------------------------------
// Dynamic position-bias MLP (all fp32): 225 rows, 3 stages of LN->ReLU->W.
// ---------------------------------------------------------------------------
__global__ __launch_bounds__(256) void k_posmlp(
    const float* __restrict__ pp_w, const float* __restrict__ pp_b,
    const float* __restrict__ p1_g, const float* __restrict__ p1_b,
    const float* __restrict__ p1_w, const float* __restrict__ p1_bias,
    const float* __restrict__ p2_g, const float* __restrict__ p2_b,
    const float* __restrict__ p2_w, const float* __restrict__ p2_bias,
    const float* __restrict__ p3_g, const float* __restrict__ p3_b,
    const float* __restrict__ p3_w, const float* __restrict__ p3_bias,
    float* __restrict__ pos) {
    int i = threadIdx.x;
    if (i >= 225) return;
    float bh = (float)(i / 15 - 7), bw = (float)(i % 15 - 7);
    float v[12], u[12];
#pragma unroll
    for (int j = 0; j < 12; j++)
        v[j] = bh * pp_w[j] + bw * pp_w[12 + j] + pp_b[j];

    auto stage = [&](const float* gg, const float* bb2, const float* Wm, const float* bs, int OD) {
        float mean = 0.f;
        for (int j = 0; j < 12; j++) mean += v[j];
        mean *= (1.0f / 12.0f);
        float var = 0.f;
        for (int j = 0; j < 12; j++) { float d = v[j] - mean; var += d * d; }
        var *= (1.0f / 12.0f);
        float rs = rsqrtf(var + 1e-5f);
        for (int j = 0; j < 12; j++)
            u[j] = fmaxf((v[j] - mean) * rs * gg[j] + bb2[j], 0.0f);
        for (int o = 0; o < OD; o++) {
            float a = bs[o];
            for (int j = 0; j < 12; j++) a += u[j] * Wm[j * OD + o];
            v[o] = a;
        }
    };
    stage(p1_g, p1_b, p1_w, p1_bias, 12);
    stage(p2_g, p2_b, p2_w, p2_bias, 12);
    stage(p3_g, p3_b, p3_w, p3_bias, 6);
    for (int h = 0; h < 6; h++) pos[i * 6 + h] = v[h];
}

// ---------------------------------------------------------------------------
// MFMA GEMM, tile 128x192 (BN = full C width), BK=64, 4 waves, each wave a
// 32x192 sub-tile (2x12 fragments, acc = 96 VGPR). 2-buffer counted-vmcnt
// pipeline (10 loads/wave/tile). Staging via global_load_lds width=16,
// XOR-swizzled source + swizzled ds_read (conflict-free).
// EPI: 0 = bias, bf16 out              (qkv; N=576, 3 column-blocks)
//      1 = bias+GELU, bf16 out        (fc1; N=768, 4 column-blocks)
//      2 = bias+residual(y), f32 out  (fc2; N=192)
//      3 = proj fused: bias + window-reverse/shift residual from x,
//          write y (f32) + LN2 -> h2 (bf16). N=192.
// grid = (N/192, M/128).
// ---------------------------------------------------------------------------
template <int EPI, typename OutT>
__global__ __launch_bounds__(256) void k_gemm(const bf16* __restrict__ A,
                                              const bf16* __restrict__ Bt,
                                              const float* __restrict__ bias,
                                              OutT* __restrict__ Cd,
                                              int M, int N, int K,
                                              const float* __restrict__ xres,
                                              const float* __restrict__ g2,
                                              const float* __restrict__ b2,
                                              float* __restrict__ yout,
                                              bf16* __restrict__ h2out) {
    constexpr int BM = 128, BN = 192, BK = 64;
    __shared__ __align__(16) unsigned short As[2][BM * BK];  // 2 x 16 KB
    __shared__ __align__(16) unsigned short Bs[2][BN * BK];  // 2 x 24 KB
    int tid = threadIdx.x;
    int wv = tid >> 6, lane = tid & 63;
    int lm = lane & 15, quad = lane >> 4;
    int sub = lane >> 3;                       // row-within-8 for staging
    int cb8 = (((lane & 7) ^ sub) << 3);       // inverse-swizzled bf16 col
    int n0 = blockIdx.x * BN;
    int m0 = blockIdx.y * BM;

    const bf16* aSrc = A  + (size_t)(m0 + wv * 32 + sub) * K + cb8;
    const bf16* bSrc = Bt + (size_t)(n0 + wv * 48 + sub) * K + cb8;

    // 10 loads per wave per tile (4 A-chunks + 6 B-chunks of 8 rows = 1 KB)
    auto stage = [&](int buf, int k0) {
#pragma unroll
        for (int i = 0; i < 4; ++i)
            gload_lds16(aSrc + (size_t)(i * 8) * K + k0,
                        &As[buf][(wv * 32 + i * 8) * 64]);
#pragma unroll
        for (int i = 0; i < 6; ++i)
            gload_lds16(bSrc + (size_t)(i * 8) * K + k0,
                        &Bs[buf][(wv * 48 + i * 8) * 64]);
    };

    f32x4 acc[2][12] = {};

    auto compute = [&](int buf) {
#pragma unroll
        for (int ks = 0; ks < BK; ks += 32) {
            int xk = (ks + quad * 8) ^ ((lm & 7) << 3);  // swizzled read col
            bf16x8 af[2];
#pragma unroll
            for (int im = 0; im < 2; ++im)
                af[im] = *(const bf16x8*)&As[buf][(wv * 32 + im * 16 + lm) * 64 + xk];
#pragma unroll
            for (int in = 0; in < 12; ++in) {
                bf16x8 bq = *(const bf16x8*)&Bs[buf][(in * 16 + lm) * 64 + xk];
#pragma unroll
                for (int im = 0; im < 2; ++im)
                    acc[im][in] = __builtin_amdgcn_mfma_f32_16x16x32_bf16(
                        af[im], bq, acc[im][in], 0, 0, 0);
            }
        }
    };

    const int nt = K / BK;      // 3 or 12
    stage(0, 0);
    stage(1, BK);
    int cur = 0;
    for (int t = 0; t < nt; ++t) {
        if (t + 1 < nt)
            asm volatile("s_waitcnt vmcnt(10)" ::: "memory");  // tile t resident
        else
            asm volatile("s_waitcnt vmcnt(0)" ::: "memory");
        __builtin_amdgcn_s_barrier();
        compute(cur);
        if (t + 2 < nt) {
            __builtin_amdgcn_s_barrier();   // all waves done reading cur
            stage(cur, (t + 2) * BK);
        }
        cur ^= 1;
    }

    // ---- epilogue: C/D layout col=lane&15, row=quad*4+reg ----
    if (EPI == 0 || EPI == 1) {
#pragma unroll
        for (int im = 0; im < 2; ++im) {
            int rbase = m0 + wv * 32 + im * 16 + quad * 4;
#pragma unroll
            for (int in = 0; in < 12; ++in) {
                int cg = n0 + in * 16 + lm;
                float bv = bias[cg];
#pragma unroll
                for (int r = 0; r < 4; ++r) {
                    float v = acc[im][in][r] + bv;
                    if (EPI == 1) v = 0.5f * v * (1.0f + erff(v * 0.70710678118654752f));
                    Cd[(size_t)(rbase + r) * N + cg] = (OutT)v;
                }
            }
        }
    } else if (EPI == 2) {
        // fc2: rows are image tokens; += y residual, write y (f32)
#pragma unroll
        for (int im = 0; im < 2; ++im) {
            int rbase = m0 + wv * 32 + im * 16 + quad * 4;
#pragma unroll
            for (int in = 0; in < 12; ++in) {
                int cg = in * 16 + lm;
                float bv = bias[cg];
#pragma unroll
                for (int r = 0; r < 4; ++r) {
                    size_t o = (size_t)(rbase + r) * 192 + cg;
                    yout[o] = acc[im][in][r] + bv + yout[o];
                }
            }
        }
    } else {
        // proj fused: rows are window tokens; residual from shifted x,
        // write y (image layout, f32), then LN2 -> h2 (bf16).
#pragma unroll
        for (int im = 0; im < 2; ++im) {
            int rbase = m0 + wv * 32 + im * 16 + quad * 4;
#pragma unroll
            for (int r = 0; r < 4; ++r) {
                int grow = rbase + r;                 // window token
                int w = grow >> 6, n = grow & 63;
                int bb = w >> 8, wy = (w >> 4) & 15, wx = w & 15;
                int iy = n >> 3, ix = n & 7;
                int hs = (wy * 8 + iy + 4) & 127;
                int vs = (wx * 8 + ix + 4) & 127;
                size_t xrow = ((size_t)bb * 16384 + (size_t)hs * 128 + vs) * 192;
                float vv[12];
                float s = 0.f, q = 0.f;
#pragma unroll
                for (int in = 0; in < 12; ++in) {
                    int col = in * 16 + lm;
                    float v = acc[im][in][r] + bias[col] + nz(xres[xrow + col]);
                    yout[xrow + col] = v;
                    vv[in] = v; s += v; q += v * v;
                }
#pragma unroll
                for (int o = 1; o < 16; o <<= 1) {
                    s += __shfl_xor(s, o); q += __shfl_xor(q, o);
                }
                float mean = s * (1.0f / 192.0f);
                float var = q * (1.0f / 192.0f) - mean * mean;
                float rsv = rsqrtf(var + 1e-5f);
#pragma unroll
                for (int in = 0; in < 12; ++in) {
                    int col = in * 16 + lm;
                    h2out[xrow + col] = f2bf((vv[in] - mean) * rsv * g2[col] + b2[col]);
                }
            }
        }
    }
}

// ---------------------------------------------------------------------------
// MFMA attention: one block per window, 4 waves, 6 heads sequential.
// ---------------------------------------------------------------------------
__global__ __launch_bounds__(256) void k_attn(const bf16* __restrict__ qkv,
                                              const float* __restrict__ pos,
                                              bf16* __restrict__ outp) {
    __shared__ __align__(16) unsigned short Qs[64 * 40];  // 32 + 8 pad
    __shared__ __align__(16) unsigned short Ks[64 * 40];
    __shared__ __align__(16) unsigned short Vt[32 * 72];  // transposed: [d][m]
    __shared__ __align__(16) unsigned short Ps[64 * 72];
    int w = blockIdx.x, tid = threadIdx.x;
    int wv = tid >> 6, lane = tid & 63;
    int lm = lane & 15, quad = lane >> 4;
    int wy = (w >> 4) & 15, wx = w & 15;
    bool edge = (wy == 15) || (wx == 15);
    const float scale = 0.17677669529663687f;  // 32^-0.5

    int srow = tid >> 2, scol = (tid & 3) << 3;
    const unsigned short* gq =
        (const unsigned short*)qkv + ((size_t)w * 64 + srow) * 576 + scol;

    int nbase = wv * 16 + quad * 4;

    for (int h = 0; h < 6; ++h) {
        uint4 uq = *(const uint4*)(gq + h * 32);
        uint4 uk = *(const uint4*)(gq + h * 32 + 192);
        uint4 uv = *(const uint4*)(gq + h * 32 + 384);
        *(uint4*)&Qs[srow * 40 + scol] = uq;
        *(uint4*)&Ks[srow * 40 + scol] = uk;
        const unsigned short* pv = (const unsigned short*)&uv;
#pragma unroll
        for (int j = 0; j < 8; j++) Vt[(scol + j) * 72 + srow] = pv[j];
        __syncthreads();

        f32x4 acc[4];
        bf16x8 af = *(const bf16x8*)&Qs[(wv * 16 + lm) * 40 + quad * 8];
#pragma unroll
        for (int ct = 0; ct < 4; ++ct) {
            bf16x8 bfk = *(const bf16x8*)&Ks[(ct * 16 + lm) * 40 + quad * 8];
            f32x4 z = {0.f, 0.f, 0.f, 0.f};
            acc[ct] = __builtin_amdgcn_mfma_f32_16x16x32_bf16(af, bfk, z, 0, 0, 0);
        }

        float sv[4][4];
#pragma unroll
        for (int ct = 0; ct < 4; ++ct) {
            int m = ct * 16 + lm;
            int iym = m >> 3, ixm = m & 7;
            int hm = wy * 8 + iym, wm = wx * 8 + ixm;
            int ridm = (hm < 120 ? 0 : (hm < 124 ? 1 : 2)) * 3 +
                       (wm < 120 ? 0 : (wm < 124 ? 1 : 2));
#pragma unroll
            for (int r = 0; r < 4; r++) {
                int n = nbase + r;
                int iyn = n >> 3, ixn = n & 7;
                float s = acc[ct][r] * scale +
                          pos[((iyn - iym + 7) * 15 + (ixn - ixm + 7)) * 6 + h];
                if (edge) {
                    int hn = wy * 8 + iyn, wn = wx * 8 + ixn;
                    int ridn = (hn < 120 ? 0 : (hn < 124 ? 1 : 2)) * 3 +
                               (wn < 120 ? 0 : (wn < 124 ? 1 : 2));
                    if (ridn != ridm) s -= 100.0f;
                }
                sv[ct][r] = s;
            }
        }

#pragma unroll
        for (int r = 0; r < 4; r++) {
            float mx = fmaxf(fmaxf(sv[0][r], sv[1][r]), fmaxf(sv[2][r], sv[3][r]));
#pragma unroll
            for (int o = 1; o < 16; o <<= 1) mx = fmaxf(mx, __shfl_xor(mx, o));
            float e0 = expf(sv[0][r] - mx), e1 = expf(sv[1][r] - mx);
            float e2 = expf(sv[2][r] - mx), e3 = expf(sv[3][r] - mx);
            float sum = e0 + e1 + e2 + e3;
#pragma unroll
            for (int o = 1; o < 16; o <<= 1) sum += __shfl_xor(sum, o);
            float inv = 1.0f / sum;
            int n = nbase + r;
            *(bf16*)&Ps[n * 72 + lm]      = f2bf(e0 * inv);
            *(bf16*)&Ps[n * 72 + 16 + lm] = f2bf(e1 * inv);
            *(bf16*)&Ps[n * 72 + 32 + lm] = f2bf(e2 * inv);
            *(bf16*)&Ps[n * 72 + 48 + lm] = f2bf(e3 * inv);
        }
        __syncthreads();

        f32x4 o0 = {0.f, 0.f, 0.f, 0.f}, o1 = {0.f, 0.f, 0.f, 0.f};
#pragma unroll
        for (int kc = 0; kc < 2; kc++) {
            bf16x8 pa = *(const bf16x8*)&Ps[(wv * 16 + lm) * 72 + kc * 32 + quad * 8];
            bf16x8 vb0 = *(const bf16x8*)&Vt[lm * 72 + kc * 32 + quad * 8];
            bf16x8 vb1 = *(const bf16x8*)&Vt[(16 + lm) * 72 + kc * 32 + quad * 8];
            o0 = __builtin_amdgcn_mfma_f32_16x16x32_bf16(pa, vb0, o0, 0, 0, 0);
            o1 = __builtin_amdgcn_mfma_f32_16x16x32_bf16(pa, vb1, o1, 0, 0, 0);
        }
#pragma unroll
        for (int r = 0; r < 4; r++) {
            int n = nbase + r;
            size_t base = ((size_t)w * 64 + n) * 192 + h * 32;
            outp[base + lm]      = f2bf(o0[r]);
            outp[base + 16 + lm] = f2bf(o1[r]);
        }
        __syncthreads();
    }
}

// ---------------------------------------------------------------------------
extern "C" void kernel_launch(void* const* d_in, const int* in_sizes, int n_in,
                              void* d_out, int out_size, void* d_ws, size_t ws_size,
                              hipStream_t stream) {
    (void)in_sizes; (void)n_in; (void)out_size;
    const float* x      = (const float*)d_in[0];
    const float* n1_g   = (const float*)d_in[4];
    const float* n1_b   = (const float*)d_in[5];
    const float* qkv_w  = (const float*)d_in[6];
    const float* qkv_b  = (const float*)d_in[7];
    const float* proj_w = (const float*)d_in[8];
    const float* proj_b = (const float*)d_in[9];
    const float* pp_w   = (const float*)d_in[10];
    const float* pp_b   = (const float*)d_in[11];
    const float* p1_g   = (const float*)d_in[12];
    const float* p1_b   = (const float*)d_in[13];
    const float* p1_w   = (const float*)d_in[14];
    const float* p1_bias= (const float*)d_in[15];
    const float* p2_g   = (const float*)d_in[16];
    const float* p2_b   = (const float*)d_in[17];
    const float* p2_w   = (const float*)d_in[18];
    const float* p2_bias= (const float*)d_in[19];
    const float* p3_g   = (const float*)d_in[20];
    const float* p3_b   = (const float*)d_in[21];
    const float* p3_w   = (const float*)d_in[22];
    const float* p3_bias= (const float*)d_in[23];
    const float* n2_g   = (const float*)d_in[24];
    const float* n2_b   = (const float*)d_in[25];
    const float* fc1_w  = (const float*)d_in[26];
    const float* fc1_b  = (const float*)d_in[27];
    const float* fc2_w  = (const float*)d_in[28];
    const float* fc2_b  = (const float*)d_in[29];

    char* ws = (char*)d_ws;
    size_t off = 0;
    auto alloc = [&](size_t bytes) -> char* {
        char* p = ws + off;
        off += (bytes + 255) & ~(size_t)255;
        return p;
    };
    // bf16 weight copies + pos (~0.9 MB)
    bf16* qkvwT  = (bf16*)alloc((size_t)CDIM * 576 * 2);
    bf16* projwT = (bf16*)alloc((size_t)CDIM * CDIM * 2);
    bf16* fc1wT  = (bf16*)alloc((size_t)CDIM * HIDDEN * 2);
    bf16* fc2wT  = (bf16*)alloc((size_t)HIDDEN * CDIM * 2);
    float* pos   = (float*)alloc(225 * 6 * 4);

    const size_t flatNeed = (size_t)ROWS * CDIM * 2       // region0 (xw/attn)
                          + (size_t)ROWS * HIDDEN * 2     // region1 (qkv->fc1)
                          + (size_t)ROWS * CDIM * 2       // h2
                          + (1u << 20);
    const bool flat = (ws_size > off) && ((ws_size - off) >= flatNeed);
    const int NCH = flat ? 1 : 8;
    const int NIMG = flat ? 8 : 1;
    const size_t R = (size_t)16384 * NIMG;   // rows per chunk

    bf16 *xw_b, *qkv_buf, *attn_b, *h2_b, *fc1_buf;
    if (flat) {
        bf16* region0 = (bf16*)alloc((size_t)ROWS * CDIM * 2);
        bf16* region1 = (bf16*)alloc((size_t)ROWS * HIDDEN * 2);
        h2_b = (bf16*)alloc((size_t)ROWS * CDIM * 2);
        xw_b = attn_b = region0;          // sequential lifetimes
        qkv_buf = region1;                // dead after attn
        fc1_buf = region1;                // reuses qkv space
    } else {
        xw_b     = (bf16*)alloc(R * CDIM * 2);
        qkv_buf  = (bf16*)alloc(R * 576 * 2);
        attn_b   = (bf16*)alloc(R * CDIM * 2);
        h2_b     = (bf16*)alloc(R * CDIM * 2);
        fc1_buf  = (bf16*)alloc(R * HIDDEN * 2);
    }
    float* yout = (float*)d_out;

    // prep (tiny)
    k_transpose<<<(CDIM * 576 + 255) / 256, 256, 0, stream>>>(qkv_w, qkvwT, CDIM, 576);
    k_transpose<<<(CDIM * CDIM + 255) / 256, 256, 0, stream>>>(proj_w, projwT, CDIM, CDIM);
    k_transpose<<<(CDIM * HIDDEN + 255) / 256, 256, 0, stream>>>(fc1_w, fc1wT, CDIM, HIDDEN);
    k_transpose<<<(HIDDEN * CDIM + 255) / 256, 256, 0, stream>>>(fc2_w, fc2wT, HIDDEN, CDIM);
    k_posmlp<<<1, 256, 0, stream>>>(pp_w, pp_b, p1_g, p1_b, p1_w, p1_bias,
                                    p2_g, p2_b, p2_w, p2_bias,
                                    p3_g, p3_b, p3_w, p3_bias, pos);

    for (int c = 0; c < NCH; ++c) {
        const float* x_c = x + (size_t)c * 16384 * CDIM;
        float* y_c = yout + (size_t)c * 16384 * CDIM;

        k_ln1_part<<<(int)(R / 4), 256, 0, stream>>>(x_c, n1_g, n1_b, xw_b);

        k_gemm<0, bf16><<<dim3(576 / 192, (int)(R / 128)), 256, 0, stream>>>(
            xw_b, qkvwT, qkv_b, qkv_buf, (int)R, 576, CDIM,
            nullptr, nullptr, nullptr, nullptr, nullptr);

        k_attn<<<(int)(R / 64), 256, 0, stream>>>(qkv_buf, pos, attn_b);

        // proj + window-reverse residual + LN2 fused: writes y and h2
        k_gemm<3, bf16><<<dim3(1, (int)(R / 128)), 256, 0, stream>>>(
            attn_b, projwT, proj_b, (bf16*)nullptr, (int)R, CDIM, CDIM,
            x_c, n2_g, n2_b, y_c, h2_b);

        k_gemm<1, bf16><<<dim3(HIDDEN / 192, (int)(R / 128)), 256, 0, stream>>>(
            h2_b, fc1wT, fc1_b, fc1_buf, (int)R, HIDDEN, CDIM,
            nullptr, nullptr, nullptr, nullptr, nullptr);

        k_gemm<2, float><<<dim3(1, (int)(R / 128)), 256, 0, stream>>>(
            fc1_buf, fc2wT, fc2_b, y_c, (int)R, CDIM, HIDDEN,
            nullptr, nullptr, nullptr, y_c, nullptr);
    }
}

// Round 5
// 646.189 us; speedup vs baseline: 1.1411x; 1.0483x over previous
//
#include <hip/hip_runtime.h>
#include <hip/hip_bf16.h>
#include <math.h>

using bf16 = __hip_bfloat16;

typedef __bf16 bf16x8 __attribute__((ext_vector_type(8)));
typedef float f32x4 __attribute__((ext_vector_type(4)));

__device__ __forceinline__ float bf2f(bf16 v) { return __bfloat162float(v); }
__device__ __forceinline__ bf16 f2bf(float v) { return __float2bfloat16(v); }
__device__ __forceinline__ float nz(float v) { return (v == v) ? v : 0.0f; }

// async global -> LDS, 16 bytes per lane (wave writes base + lane*16)
__device__ __forceinline__ void gload_lds16(const void* g, void* l) {
    __builtin_amdgcn_global_load_lds(
        (const __attribute__((address_space(1))) unsigned int*)g,
        (__attribute__((address_space(3))) unsigned int*)l, 16, 0, 0);
}

// fast GELU: v * sigmoid(v*(1.5957691 + 0.07135481*v^2))  (tanh-approx form)
__device__ __forceinline__ float fgelu(float v) {
    float z = v * (1.5957691f + 0.07135481f * v * v);
    return v / (1.0f + __expf(-z));
}

// Problem constants
#define CDIM 192
#define NHEADS 6
#define ROWS 131072        // 8 * 128 * 128
#define HIDDEN 768

// ---------------------------------------------------------------------------
// K1: LN1 + cyclic shift (-4,-4) + window partition. One wave per token.
// ---------------------------------------------------------------------------
__global__ __launch_bounds__(256) void k_ln1_part(const float* __restrict__ x,
                                                  const float* __restrict__ g,
                                                  const float* __restrict__ bta,
                                                  bf16* __restrict__ xw) {
    int tid = threadIdx.x;
    int lane = tid & 63;
    int t = (blockIdx.x << 2) + (tid >> 6);   // chunk-local token id
    int w = t >> 6, n = t & 63;
    int bb = w >> 8, wy = (w >> 4) & 15, wx = w & 15;
    int iy = n >> 3, ix = n & 7;
    int hs = (wy * 8 + iy + 4) & 127;
    int vs = (wx * 8 + ix + 4) & 127;
    const float* xr = x + ((size_t)bb * 16384 + (size_t)hs * 128 + vs) * CDIM;
    float v0 = nz(xr[lane]);
    float v1 = nz(xr[lane + 64]);
    float v2 = nz(xr[lane + 128]);
    float s = v0 + v1 + v2;
    float q = v0 * v0 + v1 * v1 + v2 * v2;
#pragma unroll
    for (int o = 32; o > 0; o >>= 1) { s += __shfl_xor(s, o); q += __shfl_xor(q, o); }
    float mean = s * (1.0f / 192.0f);
    float var = q * (1.0f / 192.0f) - mean * mean;
    float rs = rsqrtf(var + 1e-5f);
    bf16* orow = xw + (size_t)t * CDIM;
    orow[lane]       = f2bf((v0 - mean) * rs * g[lane]       + bta[lane]);
    orow[lane + 64]  = f2bf((v1 - mean) * rs * g[lane + 64]  + bta[lane + 64]);
    orow[lane + 128] = f2bf((v2 - mean) * rs * g[lane + 128] + bta[lane + 128]);
}

// ---------------------------------------------------------------------------
// Weight transpose + fp32->bf16: in[K,N] f32 -> out[N,K] bf16
// ---------------------------------------------------------------------------
__global__ void k_transpose(const float* __restrict__ in, bf16* __restrict__ out, int K, int N) {
    int i = blockIdx.x * 256 + threadIdx.x;
    if (i < K * N) {
        int k = i / N, n = i - k * N;
        out[(size_t)n * K + k] = f2bf(in[i]);
    }
}

// ---------------------------------------------------------------------------
// Dynamic position-bias MLP (all fp32): 225 rows, 3 stages of LN->ReLU->W.
// ---------------------------------------------------------------------------
__global__ __launch_bounds__(256) void k_posmlp(
    const float* __restrict__ pp_w, const float* __restrict__ pp_b,
    const float* __restrict__ p1_g, const float* __restrict__ p1_b,
    const float* __restrict__ p1_w, const float* __restrict__ p1_bias,
    const float* __restrict__ p2_g, const float* __restrict__ p2_b,
    const float* __restrict__ p2_w, const float* __restrict__ p2_bias,
    const float* __restrict__ p3_g, const float* __restrict__ p3_b,
    const float* __restrict__ p3_w, const float* __restrict__ p3_bias,
    float* __restrict__ pos) {
    int i = threadIdx.x;
    if (i >= 225) return;
    float bh = (float)(i / 15 - 7), bw = (float)(i % 15 - 7);
    float v[12], u[12];
#pragma unroll
    for (int j = 0; j < 12; j++)
        v[j] = bh * pp_w[j] + bw * pp_w[12 + j] + pp_b[j];

    auto stage = [&](const float* gg, const float* bb2, const float* Wm, const float* bs, int OD) {
        float mean = 0.f;
        for (int j = 0; j < 12; j++) mean += v[j];
        mean *= (1.0f / 12.0f);
        float var = 0.f;
        for (int j = 0; j < 12; j++) { float d = v[j] - mean; var += d * d; }
        var *= (1.0f / 12.0f);
        float rs = rsqrtf(var + 1e-5f);
        for (int j = 0; j < 12; j++)
            u[j] = fmaxf((v[j] - mean) * rs * gg[j] + bb2[j], 0.0f);
        for (int o = 0; o < OD; o++) {
            float a = bs[o];
            for (int j = 0; j < 12; j++) a += u[j] * Wm[j * OD + o];
            v[o] = a;
        }
    };
    stage(p1_g, p1_b, p1_w, p1_bias, 12);
    stage(p2_g, p2_b, p2_w, p2_bias, 12);
    stage(p3_g, p3_b, p3_w, p3_bias, 6);
    for (int h = 0; h < 6; h++) pos[i * 6 + h] = v[h];
}

// ---------------------------------------------------------------------------
// MFMA GEMM, tile 128x192 (BN = full C width), BK=64, 4 waves, each wave a
// 32x192 sub-tile (2x12 fragments). 2-buffer counted-vmcnt pipeline.
// EPI: 0 = bias, bf16 out (qkv)
//      3 = proj fused: bias + window-reverse/shift residual from x,
//          write y (f32) + LN2 -> h2 (bf16). N=192.
// grid = (N/192, M/128).
// ---------------------------------------------------------------------------
template <int EPI, typename OutT>
__global__ __launch_bounds__(256) void k_gemm(const bf16* __restrict__ A,
                                              const bf16* __restrict__ Bt,
                                              const float* __restrict__ bias,
                                              OutT* __restrict__ Cd,
                                              int M, int N, int K,
                                              const float* __restrict__ xres,
                                              const float* __restrict__ g2,
                                              const float* __restrict__ b2,
                                              float* __restrict__ yout,
                                              bf16* __restrict__ h2out) {
    constexpr int BM = 128, BN = 192, BK = 64;
    __shared__ __align__(16) unsigned short As[2][BM * BK];  // 2 x 16 KB
    __shared__ __align__(16) unsigned short Bs[2][BN * BK];  // 2 x 24 KB
    int tid = threadIdx.x;
    int wv = tid >> 6, lane = tid & 63;
    int lm = lane & 15, quad = lane >> 4;
    int sub = lane >> 3;                       // row-within-8 for staging
    int cb8 = (((lane & 7) ^ sub) << 3);       // inverse-swizzled bf16 col
    int n0 = blockIdx.x * BN;
    int m0 = blockIdx.y * BM;

    const bf16* aSrc = A  + (size_t)(m0 + wv * 32 + sub) * K + cb8;
    const bf16* bSrc = Bt + (size_t)(n0 + wv * 48 + sub) * K + cb8;

    auto stage = [&](int buf, int k0) {
#pragma unroll
        for (int i = 0; i < 4; ++i)
            gload_lds16(aSrc + (size_t)(i * 8) * K + k0,
                        &As[buf][(wv * 32 + i * 8) * 64]);
#pragma unroll
        for (int i = 0; i < 6; ++i)
            gload_lds16(bSrc + (size_t)(i * 8) * K + k0,
                        &Bs[buf][(wv * 48 + i * 8) * 64]);
    };

    f32x4 acc[2][12] = {};

    auto compute = [&](int buf) {
#pragma unroll
        for (int ks = 0; ks < BK; ks += 32) {
            int xk = (ks + quad * 8) ^ ((lm & 7) << 3);  // swizzled read col
            bf16x8 af[2];
#pragma unroll
            for (int im = 0; im < 2; ++im)
                af[im] = *(const bf16x8*)&As[buf][(wv * 32 + im * 16 + lm) * 64 + xk];
#pragma unroll
            for (int in = 0; in < 12; ++in) {
                bf16x8 bq = *(const bf16x8*)&Bs[buf][(in * 16 + lm) * 64 + xk];
#pragma unroll
                for (int im = 0; im < 2; ++im)
                    acc[im][in] = __builtin_amdgcn_mfma_f32_16x16x32_bf16(
                        af[im], bq, acc[im][in], 0, 0, 0);
            }
        }
    };

    const int nt = K / BK;      // 3
    stage(0, 0);
    stage(1, BK);
    int cur = 0;
    for (int t = 0; t < nt; ++t) {
        if (t + 1 < nt)
            asm volatile("s_waitcnt vmcnt(10)" ::: "memory");
        else
            asm volatile("s_waitcnt vmcnt(0)" ::: "memory");
        __builtin_amdgcn_s_barrier();
        compute(cur);
        if (t + 2 < nt) {
            __builtin_amdgcn_s_barrier();
            stage(cur, (t + 2) * BK);
        }
        cur ^= 1;
    }

    // ---- epilogue: C/D layout col=lane&15, row=quad*4+reg ----
    if (EPI == 0) {
#pragma unroll
        for (int im = 0; im < 2; ++im) {
            int rbase = m0 + wv * 32 + im * 16 + quad * 4;
#pragma unroll
            for (int in = 0; in < 12; ++in) {
                int cg = n0 + in * 16 + lm;
                float bv = bias[cg];
#pragma unroll
                for (int r = 0; r < 4; ++r) {
                    float v = acc[im][in][r] + bv;
                    Cd[(size_t)(rbase + r) * N + cg] = (OutT)v;
                }
            }
        }
    } else {
        // proj fused: rows are window tokens; residual from shifted x,
        // write y (image layout, f32), then LN2 -> h2 (bf16).
#pragma unroll
        for (int im = 0; im < 2; ++im) {
            int rbase = m0 + wv * 32 + im * 16 + quad * 4;
#pragma unroll
            for (int r = 0; r < 4; ++r) {
                int grow = rbase + r;                 // window token
                int w = grow >> 6, n = grow & 63;
                int bb = w >> 8, wy = (w >> 4) & 15, wx = w & 15;
                int iy = n >> 3, ix = n & 7;
                int hs = (wy * 8 + iy + 4) & 127;
                int vs = (wx * 8 + ix + 4) & 127;
                size_t xrow = ((size_t)bb * 16384 + (size_t)hs * 128 + vs) * 192;
                float vv[12];
                float s = 0.f, q = 0.f;
#pragma unroll
                for (int in = 0; in < 12; ++in) {
                    int col = in * 16 + lm;
                    float v = acc[im][in][r] + bias[col] + nz(xres[xrow + col]);
                    yout[xrow + col] = v;
                    vv[in] = v; s += v; q += v * v;
                }
#pragma unroll
                for (int o = 1; o < 16; o <<= 1) {
                    s += __shfl_xor(s, o); q += __shfl_xor(q, o);
                }
                float mean = s * (1.0f / 192.0f);
                float var = q * (1.0f / 192.0f) - mean * mean;
                float rsv = rsqrtf(var + 1e-5f);
#pragma unroll
                for (int in = 0; in < 12; ++in) {
                    int col = in * 16 + lm;
                    h2out[xrow + col] = f2bf((vv[in] - mean) * rsv * g2[col] + b2[col]);
                }
            }
        }
    }
}

// ---------------------------------------------------------------------------
// Fused MLP: y += fc2(GELU(fc1(h2))). One block per 128 rows, 512 threads
// (8 waves, wave owns 16 rows x 192 cols). Hidden activations (128x768)
// never touch HBM: per kb (4 blocks of 192 hidden cols):
//   GEMM1: a1 = h2_tile @ w1t[kb]      (A resident in LDS, staged once)
//   GELU(a1+b1) -> Ps (LDS, swizzled)  (wave writes/reads only its own rows)
//   GEMM2: a2 += Ps @ w2t[:, kb-slice]
// B chunks (24 x 24KB, all L2-resident weights) stream through a 2-slot
// ring with counted vmcnt(3); 2 barriers per chunk.
// LDS: A 48KB + Bring 48KB + Ps 48KB + bias 3KB = 147KB -> 1 block/CU.
// ---------------------------------------------------------------------------
__global__ __launch_bounds__(512) void k_mlp(const bf16* __restrict__ h2,
                                             const bf16* __restrict__ w1t,  // [768][192]
                                             const float* __restrict__ b1,  // [768]
                                             const bf16* __restrict__ w2t,  // [192][768]
                                             const float* __restrict__ b2,  // [192]
                                             float* __restrict__ y,
                                             int M) {
    __shared__ __align__(16) unsigned short Ah[3 * 128 * 64];   // 48 KB (3 planes)
    __shared__ __align__(16) unsigned short Bb[2][192 * 64];    // 48 KB ring
    __shared__ __align__(16) unsigned short Ps[3 * 128 * 64];   // 48 KB
    __shared__ float b1s[HIDDEN];                               // 3 KB
    int tid = threadIdx.x;
    int wv = tid >> 6, lane = tid & 63;
    int lm = lane & 15, quad = lane >> 4;
    int sub = lane >> 3;
    int cb8 = (((lane & 7) ^ sub) << 3);
    int m0 = blockIdx.x * 128;

    // fc1 bias -> LDS (loads are oldest; drained by first vmcnt wait)
    for (int i = tid; i < HIDDEN; i += 512) b1s[i] = b1[i];

    // stage A (h2 tile) once: 3 planes x 16 row-blocks = 48 x 1KB loads, 6/wave
#pragma unroll
    for (int i = 0; i < 6; ++i) {
        int j = wv * 6 + i;
        int p = j >> 4, r0 = (j & 15) * 8;
        gload_lds16(h2 + (size_t)(m0 + r0 + sub) * 192 + p * 64 + cb8,
                    &Ah[p * 8192 + r0 * 64]);
    }

    // B chunk c (0..23): kb=c/6, ph=c%6. ph<3: w1t rows kb*192.. (stride 192),
    // cols ph*64. ph>=3: w2t rows 0..191 (stride 768), cols kb*192+(ph-3)*64.
    auto stageChunk = [&](int c) {
        int kb = c / 6, ph = c % 6, slot = c & 1;
        if (ph < 3) {
            const bf16* s = w1t + (size_t)(kb * 192 + wv * 24 + sub) * 192 + ph * 64 + cb8;
#pragma unroll
            for (int i = 0; i < 3; ++i)
                gload_lds16(s + (size_t)(i * 8) * 192, &Bb[slot][(wv * 24 + i * 8) * 64]);
        } else {
            const bf16* s = w2t + (size_t)(wv * 24 + sub) * 768 + kb * 192 + (ph - 3) * 64 + cb8;
#pragma unroll
            for (int i = 0; i < 3; ++i)
                gload_lds16(s + (size_t)(i * 8) * 768, &Bb[slot][(wv * 24 + i * 8) * 64]);
        }
    };

    f32x4 a1[12];
    f32x4 a2[12] = {};

    // compute: acc[in] += Aplane-frag x Bb[slot][in]-frag  (K=64, two 32-steps)
    auto docompute = [&](const unsigned short* Ap, int slot, f32x4 (&acc)[12]) {
#pragma unroll
        for (int ks = 0; ks < 64; ks += 32) {
            int xk = (ks + quad * 8) ^ ((lm & 7) << 3);
            bf16x8 af = *(const bf16x8*)&Ap[(wv * 16 + lm) * 64 + xk];
#pragma unroll
            for (int in = 0; in < 12; ++in) {
                bf16x8 bq = *(const bf16x8*)&Bb[slot][(in * 16 + lm) * 64 + xk];
                acc[in] = __builtin_amdgcn_mfma_f32_16x16x32_bf16(af, bq, acc[in], 0, 0, 0);
            }
        }
    };

    stageChunk(0);
    stageChunk(1);
    asm volatile("s_waitcnt lgkmcnt(0)" ::: "memory");  // b1s writes drained

    for (int c = 0; c < 24; ++c) {
        if (c < 22)
            asm volatile("s_waitcnt vmcnt(3)" ::: "memory");  // chunk c resident
        else
            asm volatile("s_waitcnt vmcnt(0)" ::: "memory");
        __builtin_amdgcn_s_barrier();
        int kb = c / 6, ph = c % 6, slot = c & 1;
        if (ph == 0) {
#pragma unroll
            for (int in = 0; in < 12; ++in) a1[in] = (f32x4){0.f, 0.f, 0.f, 0.f};
        }
        if (ph < 3)
            docompute(&Ah[ph * 8192], slot, a1);
        else
            docompute(&Ps[(ph - 3) * 8192], slot, a2);
        __builtin_amdgcn_s_barrier();
        if (c + 2 < 24) stageChunk(c + 2);
        if (ph == 2) {
            // GELU(a1 + b1) -> Ps (swizzled). Within-wave rows only.
#pragma unroll
            for (int in = 0; in < 12; ++in) {
                int col = in * 16 + lm;
                float bv = b1s[kb * 192 + col];
                int plane = col >> 6, c6 = col & 63;
#pragma unroll
                for (int r = 0; r < 4; ++r) {
                    int rl = wv * 16 + quad * 4 + r;
                    float ge = fgelu(a1[in][r] + bv);
                    int sc = ((((c6 >> 3) ^ (rl & 7)) << 3) | (col & 7));
                    *(bf16*)&Ps[plane * 8192 + rl * 64 + sc] = f2bf(ge);
                }
            }
        }
    }

    // epilogue: y += a2 + b2
#pragma unroll
    for (int in = 0; in < 12; ++in) {
        int col = in * 16 + lm;
        float bv = b2[col];
#pragma unroll
        for (int r = 0; r < 4; ++r) {
            size_t o = (size_t)(m0 + wv * 16 + quad * 4 + r) * 192 + col;
            y[o] = a2[in][r] + bv + y[o];
        }
    }
}

// ---------------------------------------------------------------------------
// MFMA attention: one block per window, 4 waves, 6 heads sequential.
// ---------------------------------------------------------------------------
__global__ __launch_bounds__(256) void k_attn(const bf16* __restrict__ qkv,
                                              const float* __restrict__ pos,
                                              bf16* __restrict__ outp) {
    __shared__ __align__(16) unsigned short Qs[64 * 40];
    __shared__ __align__(16) unsigned short Ks[64 * 40];
    __shared__ __align__(16) unsigned short Vt[32 * 72];
    __shared__ __align__(16) unsigned short Ps[64 * 72];
    int w = blockIdx.x, tid = threadIdx.x;
    int wv = tid >> 6, lane = tid & 63;
    int lm = lane & 15, quad = lane >> 4;
    int wy = (w >> 4) & 15, wx = w & 15;
    bool edge = (wy == 15) || (wx == 15);
    const float scale = 0.17677669529663687f;  // 32^-0.5

    int srow = tid >> 2, scol = (tid & 3) << 3;
    const unsigned short* gq =
        (const unsigned short*)qkv + ((size_t)w * 64 + srow) * 576 + scol;

    int nbase = wv * 16 + quad * 4;

    for (int h = 0; h < 6; ++h) {
        uint4 uq = *(const uint4*)(gq + h * 32);
        uint4 uk = *(const uint4*)(gq + h * 32 + 192);
        uint4 uv = *(const uint4*)(gq + h * 32 + 384);
        *(uint4*)&Qs[srow * 40 + scol] = uq;
        *(uint4*)&Ks[srow * 40 + scol] = uk;
        const unsigned short* pv = (const unsigned short*)&uv;
#pragma unroll
        for (int j = 0; j < 8; j++) Vt[(scol + j) * 72 + srow] = pv[j];
        __syncthreads();

        f32x4 acc[4];
        bf16x8 af = *(const bf16x8*)&Qs[(wv * 16 + lm) * 40 + quad * 8];
#pragma unroll
        for (int ct = 0; ct < 4; ++ct) {
            bf16x8 bfk = *(const bf16x8*)&Ks[(ct * 16 + lm) * 40 + quad * 8];
            f32x4 z = {0.f, 0.f, 0.f, 0.f};
            acc[ct] = __builtin_amdgcn_mfma_f32_16x16x32_bf16(af, bfk, z, 0, 0, 0);
        }

        float sv[4][4];
#pragma unroll
        for (int ct = 0; ct < 4; ++ct) {
            int m = ct * 16 + lm;
            int iym = m >> 3, ixm = m & 7;
            int hm = wy * 8 + iym, wm = wx * 8 + ixm;
            int ridm = (hm < 120 ? 0 : (hm < 124 ? 1 : 2)) * 3 +
                       (wm < 120 ? 0 : (wm < 124 ? 1 : 2));
#pragma unroll
            for (int r = 0; r < 4; r++) {
                int n = nbase + r;
                int iyn = n >> 3, ixn = n & 7;
                float s = acc[ct][r] * scale +
                          pos[((iyn - iym + 7) * 15 + (ixn - ixm + 7)) * 6 + h];
                if (edge) {
                    int hn = wy * 8 + iyn, wn = wx * 8 + ixn;
                    int ridn = (hn < 120 ? 0 : (hn < 124 ? 1 : 2)) * 3 +
                               (wn < 120 ? 0 : (wn < 124 ? 1 : 2));
                    if (ridn != ridm) s -= 100.0f;
                }
                sv[ct][r] = s;
            }
        }

#pragma unroll
        for (int r = 0; r < 4; r++) {
            float mx = fmaxf(fmaxf(sv[0][r], sv[1][r]), fmaxf(sv[2][r], sv[3][r]));
#pragma unroll
            for (int o = 1; o < 16; o <<= 1) mx = fmaxf(mx, __shfl_xor(mx, o));
            float e0 = expf(sv[0][r] - mx), e1 = expf(sv[1][r] - mx);
            float e2 = expf(sv[2][r] - mx), e3 = expf(sv[3][r] - mx);
            float sum = e0 + e1 + e2 + e3;
#pragma unroll
            for (int o = 1; o < 16; o <<= 1) sum += __shfl_xor(sum, o);
            float inv = 1.0f / sum;
            int n = nbase + r;
            *(bf16*)&Ps[n * 72 + lm]      = f2bf(e0 * inv);
            *(bf16*)&Ps[n * 72 + 16 + lm] = f2bf(e1 * inv);
            *(bf16*)&Ps[n * 72 + 32 + lm] = f2bf(e2 * inv);
            *(bf16*)&Ps[n * 72 + 48 + lm] = f2bf(e3 * inv);
        }
        __syncthreads();

        f32x4 o0 = {0.f, 0.f, 0.f, 0.f}, o1 = {0.f, 0.f, 0.f, 0.f};
#pragma unroll
        for (int kc = 0; kc < 2; kc++) {
            bf16x8 pa = *(const bf16x8*)&Ps[(wv * 16 + lm) * 72 + kc * 32 + quad * 8];
            bf16x8 vb0 = *(const bf16x8*)&Vt[lm * 72 + kc * 32 + quad * 8];
            bf16x8 vb1 = *(const bf16x8*)&Vt[(16 + lm) * 72 + kc * 32 + quad * 8];
            o0 = __builtin_amdgcn_mfma_f32_16x16x32_bf16(pa, vb0, o0, 0, 0, 0);
            o1 = __builtin_amdgcn_mfma_f32_16x16x32_bf16(pa, vb1, o1, 0, 0, 0);
        }
#pragma unroll
        for (int r = 0; r < 4; r++) {
            int n = nbase + r;
            size_t base = ((size_t)w * 64 + n) * 192 + h * 32;
            outp[base + lm]      = f2bf(o0[r]);
            outp[base + 16 + lm] = f2bf(o1[r]);
        }
        __syncthreads();
    }
}

// ---------------------------------------------------------------------------
extern "C" void kernel_launch(void* const* d_in, const int* in_sizes, int n_in,
                              void* d_out, int out_size, void* d_ws, size_t ws_size,
                              hipStream_t stream) {
    (void)in_sizes; (void)n_in; (void)out_size;
    const float* x      = (const float*)d_in[0];
    const float* n1_g   = (const float*)d_in[4];
    const float* n1_b   = (const float*)d_in[5];
    const float* qkv_w  = (const float*)d_in[6];
    const float* qkv_b  = (const float*)d_in[7];
    const float* proj_w = (const float*)d_in[8];
    const float* proj_b = (const float*)d_in[9];
    const float* pp_w   = (const float*)d_in[10];
    const float* pp_b   = (const float*)d_in[11];
    const float* p1_g   = (const float*)d_in[12];
    const float* p1_b   = (const float*)d_in[13];
    const float* p1_w   = (const float*)d_in[14];
    const float* p1_bias= (const float*)d_in[15];
    const float* p2_g   = (const float*)d_in[16];
    const float* p2_b   = (const float*)d_in[17];
    const float* p2_w   = (const float*)d_in[18];
    const float* p2_bias= (const float*)d_in[19];
    const float* p3_g   = (const float*)d_in[20];
    const float* p3_b   = (const float*)d_in[21];
    const float* p3_w   = (const float*)d_in[22];
    const float* p3_bias= (const float*)d_in[23];
    const float* n2_g   = (const float*)d_in[24];
    const float* n2_b   = (const float*)d_in[25];
    const float* fc1_w  = (const float*)d_in[26];
    const float* fc1_b  = (const float*)d_in[27];
    const float* fc2_w  = (const float*)d_in[28];
    const float* fc2_b  = (const float*)d_in[29];

    char* ws = (char*)d_ws;
    size_t off = 0;
    auto alloc = [&](size_t bytes) -> char* {
        char* p = ws + off;
        off += (bytes + 255) & ~(size_t)255;
        return p;
    };
    // bf16 weight copies + pos (~0.9 MB)
    bf16* qkvwT  = (bf16*)alloc((size_t)CDIM * 576 * 2);
    bf16* projwT = (bf16*)alloc((size_t)CDIM * CDIM * 2);
    bf16* fc1wT  = (bf16*)alloc((size_t)CDIM * HIDDEN * 2);
    bf16* fc2wT  = (bf16*)alloc((size_t)HIDDEN * CDIM * 2);
    float* pos   = (float*)alloc(225 * 6 * 4);

    const size_t flatNeed = (size_t)ROWS * CDIM * 2       // region0 (xw/attn)
                          + (size_t)ROWS * HIDDEN * 2     // region1 (qkv)
                          + (size_t)ROWS * CDIM * 2       // h2
                          + (1u << 20);
    const bool flat = (ws_size > off) && ((ws_size - off) >= flatNeed);
    const int NCH = flat ? 1 : 8;
    const int NIMG = flat ? 8 : 1;
    const size_t R = (size_t)16384 * NIMG;   // rows per chunk

    bf16 *xw_b, *qkv_buf, *attn_b, *h2_b;
    if (flat) {
        bf16* region0 = (bf16*)alloc((size_t)ROWS * CDIM * 2);
        bf16* region1 = (bf16*)alloc((size_t)ROWS * HIDDEN * 2);
        h2_b = (bf16*)alloc((size_t)ROWS * CDIM * 2);
        xw_b = attn_b = region0;          // sequential lifetimes
        qkv_buf = region1;
    } else {
        xw_b     = (bf16*)alloc(R * CDIM * 2);
        qkv_buf  = (bf16*)alloc(R * 576 * 2);
        attn_b   = (bf16*)alloc(R * CDIM * 2);
        h2_b     = (bf16*)alloc(R * CDIM * 2);
    }
    float* yout = (float*)d_out;

    // prep (tiny)
    k_transpose<<<(CDIM * 576 + 255) / 256, 256, 0, stream>>>(qkv_w, qkvwT, CDIM, 576);
    k_transpose<<<(CDIM * CDIM + 255) / 256, 256, 0, stream>>>(proj_w, projwT, CDIM, CDIM);
    k_transpose<<<(CDIM * HIDDEN + 255) / 256, 256, 0, stream>>>(fc1_w, fc1wT, CDIM, HIDDEN);
    k_transpose<<<(HIDDEN * CDIM + 255) / 256, 256, 0, stream>>>(fc2_w, fc2wT, HIDDEN, CDIM);
    k_posmlp<<<1, 256, 0, stream>>>(pp_w, pp_b, p1_g, p1_b, p1_w, p1_bias,
                                    p2_g, p2_b, p2_w, p2_bias,
                                    p3_g, p3_b, p3_w, p3_bias, pos);

    for (int c = 0; c < NCH; ++c) {
        const float* x_c = x + (size_t)c * 16384 * CDIM;
        float* y_c = yout + (size_t)c * 16384 * CDIM;

        k_ln1_part<<<(int)(R / 4), 256, 0, stream>>>(x_c, n1_g, n1_b, xw_b);

        k_gemm<0, bf16><<<dim3(576 / 192, (int)(R / 128)), 256, 0, stream>>>(
            xw_b, qkvwT, qkv_b, qkv_buf, (int)R, 576, CDIM,
            nullptr, nullptr, nullptr, nullptr, nullptr);

        k_attn<<<(int)(R / 64), 256, 0, stream>>>(qkv_buf, pos, attn_b);

        // proj + window-reverse residual + LN2 fused: writes y and h2
        k_gemm<3, bf16><<<dim3(1, (int)(R / 128)), 256, 0, stream>>>(
            attn_b, projwT, proj_b, (bf16*)nullptr, (int)R, CDIM, CDIM,
            x_c, n2_g, n2_b, y_c, h2_b);

        // fused MLP: y += fc2(GELU(fc1(h2)))
        k_mlp<<<(int)(R / 128), 512, 0, stream>>>(
            h2_b, fc1wT, fc1_b, fc2wT, fc2_b, y_c, (int)R);
    }
}